// Round 1
// baseline (1408.159 us; speedup 1.0000x reference)
//
#include <hip/hip_runtime.h>
#include <stdint.h>
#include <math.h>

#define Bc   8
#define Nn   38
#define NTc  9
#define ETc  4
#define Rr   416
#define Ee   378
#define Hh   128
#define Ll   12
#define GL   3

// ---------------- workspace layout (bytes) ----------------
// mn_u8   : [0, 15808)                  -> pad to 15872
// me_u8   : [15872, 15872+600704=616576)
// h0      : 616576  (38912 f = 155648B) -> 772224
// S       : 772224  (116736 f = 466944B)-> 1239168
// gnode   : 1239168 (38912 f)           -> 1394816
// gedge   : 1394816 (1161216 f = 4644864B) -> 6039680
// sn      : 6039680 (32832 f = 131328B) -> 6171008
// tn      : 6171008 (131328B)           -> 6302336
// se      : 6302336 (145152 f = 580608B)-> 6882944
// te      : 6882944 (580608B)           -> 7463552
static const size_t WS_MN    = 0;
static const size_t WS_ME    = 15872;
static const size_t WS_H0    = 616576;
static const size_t WS_S     = 772224;
static const size_t WS_GNODE = 1239168;
static const size_t WS_GEDGE = 1394816;
static const size_t WS_SN    = 6039680;
static const size_t WS_TN    = 6171008;
static const size_t WS_SE    = 6302336;
static const size_t WS_TE    = 6882944;

__device__ __forceinline__ uint8_t mval(const void* src, int i, int mode) {
  if (mode == 0) return ((const int*)src)[i] != 0;          // int32 bools
  if (mode == 1) return ((const float*)src)[i] != 0.0f;     // float bools
  return ((const uint8_t*)src)[i] != 0;                     // byte bools
}

// Normalize masks to u8 in ws. Layout auto-detected from first 256 dwords of
// mask_edge (600704 random 0/1 values -> misdetection prob ~ (1/8)^256).
__global__ void prep_masks(const void* __restrict__ mn_src, const void* __restrict__ me_src,
                           uint8_t* __restrict__ mn_dst, uint8_t* __restrict__ me_dst)
{
  __shared__ int s01, sf;
  if (threadIdx.x == 0) { s01 = 1; sf = 1; }
  __syncthreads();
  const uint32_t* p = (const uint32_t*)me_src;
  bool a01 = true, af = true;
  for (int i = threadIdx.x; i < 256; i += blockDim.x) {
    uint32_t v = p[i];
    if (v > 1u) a01 = false;
    if (v != 0u && v != 0x3f800000u) af = false;
  }
  if (!a01) atomicAnd(&s01, 0);
  if (!af)  atomicAnd(&sf, 0);
  __syncthreads();
  const int mode = s01 ? 0 : (sf ? 1 : 2);

  const int n_node = Rr * Nn;            // 15808
  const int n_edge = Rr * Nn * Nn;       // 600704
  const int tot = n_node + n_edge;
  for (int i = blockIdx.x * blockDim.x + threadIdx.x; i < tot; i += gridDim.x * blockDim.x) {
    if (i < n_node) mn_dst[i] = mval(mn_src, i, mode);
    else            me_dst[i - n_node] = mval(me_src, i - n_node, mode);
  }
}

// h0[b,n,:] = x[b,n,:] @ emb_w   (B*N*H elements, 9 FMAs each)
__global__ void h0_kernel(const float* __restrict__ x, const float* __restrict__ emb_w,
                          float* __restrict__ h0)
{
  int idx = blockIdx.x * blockDim.x + threadIdx.x;
  if (idx >= Bc * Nn * Hh) return;
  int bn = idx >> 7, o = idx & 127;
  float acc = 0.0f;
  #pragma unroll
  for (int i = 0; i < NTc; ++i) acc += x[bn * NTc + i] * emb_w[i * Hh + o];
  h0[idx] = acc;
}

// S[b,e,m,:] = h0[b,m,:] @ gc_w[0,e]
__global__ void s_kernel(const float* __restrict__ h0, const float* __restrict__ gw,
                         float* __restrict__ Sm)
{
  int idx = blockIdx.x * blockDim.x + threadIdx.x;
  if (idx >= Bc * GL * Nn * Hh) return;
  int o = idx & 127;
  int t = idx >> 7;
  int m = t % Nn; int t2 = t / Nn;
  int e = t2 % GL; int b = t2 / GL;
  float acc = 0.0f;
  for (int k = 0; k < Hh; ++k)
    acc += h0[(b * Nn + m) * Hh + k] * gw[(e * Hh + k) * Hh + o];
  Sm[idx] = acc;
}

// One block per (b, r): full 3-layer GCN on 38x128, then emit g_node / g_ne rows.
__global__ __launch_bounds__(256, 2)
void gcn_kernel(const float* __restrict__ adj, const uint8_t* __restrict__ mn,
                const uint8_t* __restrict__ me, const float* __restrict__ Sm,
                const float* __restrict__ gw, const float* __restrict__ gb,
                const int* __restrict__ isel,
                float* __restrict__ gnode, float* __restrict__ gedge)
{
  __shared__ float h[Nn][132];          // padded: bank-spread for per-row reads
  __shared__ float am[GL][Nn][Nn];
  __shared__ float sup[Nn][132];
  __shared__ float mnf[Nn];
  __shared__ float ge[Hh];

  const int tid = threadIdx.x;
  const int bid = blockIdx.x;
  const int b = bid / Rr;
  const int r = bid - b * Rr;

  // am[e] = mask_edge[r] ? adj[b,e] : 0   (e < 3)
  for (int idx = tid; idx < GL * Nn * Nn; idx += 256) {
    int e = idx / (Nn * Nn);
    int rem = idx - e * (Nn * Nn);
    int n = rem / Nn, m = rem - n * Nn;
    float a = adj[((b * ETc + e) * Nn + n) * Nn + m];
    am[e][n][m] = me[r * (Nn * Nn) + rem] ? a : 0.0f;
  }
  if (tid < Nn) mnf[tid] = mn[r * Nn + tid] ? 1.0f : 0.0f;
  __syncthreads();

  const int og = tid & 15;
  const int rg = tid >> 4;
  const int o0 = og * 8;

  float acc[3][8];

  // ---- layer 0: out = sum_e (am[e] .* col-mask) @ S[b,e], relu ----
  #pragma unroll
  for (int rr = 0; rr < 3; ++rr)
    #pragma unroll
    for (int j = 0; j < 8; ++j)
      acc[rr][j] = gb[o0 + j];

  for (int e = 0; e < GL; ++e) {
    const float* Sb = Sm + ((size_t)(b * GL + e) * Nn) * Hh;
    for (int m = 0; m < Nn; ++m) {
      float mv = mnf[m];
      float4 s0 = *(const float4*)&Sb[m * Hh + o0];
      float4 s1 = *(const float4*)&Sb[m * Hh + o0 + 4];
      #pragma unroll
      for (int rr = 0; rr < 3; ++rr) {
        int row = rg + 16 * rr;
        if (row < Nn) {
          float a = am[e][row][m] * mv;
          acc[rr][0] += a * s0.x; acc[rr][1] += a * s0.y;
          acc[rr][2] += a * s0.z; acc[rr][3] += a * s0.w;
          acc[rr][4] += a * s1.x; acc[rr][5] += a * s1.y;
          acc[rr][6] += a * s1.z; acc[rr][7] += a * s1.w;
        }
      }
    }
  }
  #pragma unroll
  for (int rr = 0; rr < 3; ++rr) {
    int row = rg + 16 * rr;
    if (row < Nn)
      #pragma unroll
      for (int j = 0; j < 8; ++j)
        h[row][o0 + j] = fmaxf(acc[rr][j], 0.0f);
  }
  __syncthreads();

  // ---- layers 1..2 ----
  for (int l = 1; l < GL; ++l) {
    float accN[3][8];
    #pragma unroll
    for (int rr = 0; rr < 3; ++rr)
      #pragma unroll
      for (int j = 0; j < 8; ++j)
        accN[rr][j] = gb[l * Hh + o0 + j];

    for (int e = 0; e < GL; ++e) {
      // sup = h @ gc_w[l][e]   (weights streamed from L2; h from LDS)
      float sacc[3][8];
      #pragma unroll
      for (int rr = 0; rr < 3; ++rr)
        #pragma unroll
        for (int j = 0; j < 8; ++j)
          sacc[rr][j] = 0.0f;

      const float* We = gw + ((size_t)(l * GL + e) * Hh) * Hh;
      for (int k = 0; k < Hh; ++k) {
        float4 w0 = *(const float4*)&We[k * Hh + o0];
        float4 w1 = *(const float4*)&We[k * Hh + o0 + 4];
        #pragma unroll
        for (int rr = 0; rr < 3; ++rr) {
          int row = rg + 16 * rr;
          float hv = (row < Nn) ? h[row][k] : 0.0f;
          sacc[rr][0] += hv * w0.x; sacc[rr][1] += hv * w0.y;
          sacc[rr][2] += hv * w0.z; sacc[rr][3] += hv * w0.w;
          sacc[rr][4] += hv * w1.x; sacc[rr][5] += hv * w1.y;
          sacc[rr][6] += hv * w1.z; sacc[rr][7] += hv * w1.w;
        }
      }
      #pragma unroll
      for (int rr = 0; rr < 3; ++rr) {
        int row = rg + 16 * rr;
        if (row < Nn) {
          *(float4*)&sup[row][o0]     = make_float4(sacc[rr][0], sacc[rr][1], sacc[rr][2], sacc[rr][3]);
          *(float4*)&sup[row][o0 + 4] = make_float4(sacc[rr][4], sacc[rr][5], sacc[rr][6], sacc[rr][7]);
        }
      }
      __syncthreads();

      // out += am[e] @ sup
      for (int m = 0; m < Nn; ++m) {
        float4 s0 = *(const float4*)&sup[m][o0];
        float4 s1 = *(const float4*)&sup[m][o0 + 4];
        #pragma unroll
        for (int rr = 0; rr < 3; ++rr) {
          int row = rg + 16 * rr;
          if (row < Nn) {
            float a = am[e][row][m];
            accN[rr][0] += a * s0.x; accN[rr][1] += a * s0.y;
            accN[rr][2] += a * s0.z; accN[rr][3] += a * s0.w;
            accN[rr][4] += a * s1.x; accN[rr][5] += a * s1.y;
            accN[rr][6] += a * s1.z; accN[rr][7] += a * s1.w;
          }
        }
      }
      __syncthreads();   // protect sup before next e overwrites it
    }
    #pragma unroll
    for (int rr = 0; rr < 3; ++rr) {
      int row = rg + 16 * rr;
      if (row < Nn)
        #pragma unroll
        for (int j = 0; j < 8; ++j)
          h[row][o0 + j] = (l < GL - 1) ? fmaxf(accN[rr][j], 0.0f) : accN[rr][j];
    }
    __syncthreads();
  }

  // ---- epilogue: graph_emb = sum_n h[n,:], emit outputs ----
  if (tid < Hh) {
    float s = 0.0f;
    for (int n = 0; n < Nn; ++n) s += h[n][tid];
    ge[tid] = s;
  }
  __syncthreads();

  if (r < Nn) {
    float* dst = gnode + (size_t)(b * Nn + r) * Hh;
    for (int o = tid; o < Hh; o += 256) dst[o] = ge[o];
  } else {
    int ei = r - Nn;
    int i0 = isel[ei * 2 + 0];
    int i1 = isel[ei * 2 + 1];
    float* dst = gedge + (size_t)(b * Ee + ei) * (3 * Hh);
    for (int o = tid; o < Hh; o += 256) {
      dst[o]           = h[i0][o];
      dst[Hh + o]      = h[i1][o];
      dst[2 * Hh + o]  = ge[o];
    }
  }
}

// node ST: all 12 layers in parallel; block = (layer, 16-row tile of 304)
__global__ __launch_bounds__(256)
void node_st_kernel(const float* __restrict__ gnode, const float* __restrict__ nw1,
                    const float* __restrict__ nb1, const float* __restrict__ nw2,
                    const float* __restrict__ nb2,
                    float* __restrict__ sn, float* __restrict__ tn)
{
  __shared__ float gbuf[16][132];
  __shared__ float hid[16][132];
  const int tid = threadIdx.x;
  const int i = blockIdx.x / 19;      // 304/16 = 19 tiles
  const int tile = blockIdx.x - i * 19;
  const int row0 = tile * 16;

  for (int idx = tid; idx < 16 * Hh; idx += 256) {
    int lr = idx >> 7, c = idx & 127;
    gbuf[lr][c] = gnode[(size_t)(row0 + lr) * Hh + c];
  }
  __syncthreads();

  const int og = tid & 15, rg = tid >> 4, o0 = og * 8;
  float hacc[8];
  #pragma unroll
  for (int j = 0; j < 8; ++j) hacc[j] = nb1[i * Hh + o0 + j];
  for (int k = 0; k < Hh; ++k) {
    const float* wp = &nw1[((size_t)i * Hh + k) * Hh + o0];
    float4 w0 = *(const float4*)wp;
    float4 w1 = *(const float4*)(wp + 4);
    float gv = gbuf[rg][k];
    hacc[0] += gv * w0.x; hacc[1] += gv * w0.y; hacc[2] += gv * w0.z; hacc[3] += gv * w0.w;
    hacc[4] += gv * w1.x; hacc[5] += gv * w1.y; hacc[6] += gv * w1.z; hacc[7] += gv * w1.w;
  }
  #pragma unroll
  for (int j = 0; j < 8; ++j) hid[rg][o0 + j] = tanhf(hacc[j]);
  __syncthreads();

  for (int idx = tid; idx < 16 * 18; idx += 256) {
    int lr = idx / 18, c = idx - lr * 18;
    int gr = row0 + lr;
    float a = nb2[i * 18 + c];
    for (int hh = 0; hh < Hh; ++hh) a += hid[lr][hh] * nw2[((size_t)i * Hh + hh) * 18 + c];
    if (c < NTc) sn[((size_t)i * (Bc * Nn) + gr) * NTc + c] = 1.0f / (1.0f + expf(-(a + 2.0f)));
    else         tn[((size_t)i * (Bc * Nn) + gr) * NTc + (c - NTc)] = a;
  }
}

// edge ST: block = (layer, 16-row tile of 3024); input width 384
__global__ __launch_bounds__(256)
void edge_st_kernel(const float* __restrict__ gedge, const float* __restrict__ ew1,
                    const float* __restrict__ eb1, const float* __restrict__ ew2,
                    const float* __restrict__ eb2,
                    float* __restrict__ se, float* __restrict__ te)
{
  __shared__ float gbuf[16][388];
  __shared__ float hid[16][132];
  const int tid = threadIdx.x;
  const int i = blockIdx.x / 189;     // 3024/16 = 189 tiles
  const int tile = blockIdx.x - i * 189;
  const int row0 = tile * 16;

  for (int idx = tid; idx < 16 * 384; idx += 256) {
    int lr = idx / 384, c = idx - lr * 384;
    gbuf[lr][c] = gedge[(size_t)(row0 + lr) * 384 + c];
  }
  __syncthreads();

  const int og = tid & 15, rg = tid >> 4, o0 = og * 8;
  float hacc[8];
  #pragma unroll
  for (int j = 0; j < 8; ++j) hacc[j] = eb1[i * Hh + o0 + j];
  for (int k = 0; k < 384; ++k) {
    const float* wp = &ew1[((size_t)i * 384 + k) * Hh + o0];
    float4 w0 = *(const float4*)wp;
    float4 w1 = *(const float4*)(wp + 4);
    float gv = gbuf[rg][k];
    hacc[0] += gv * w0.x; hacc[1] += gv * w0.y; hacc[2] += gv * w0.z; hacc[3] += gv * w0.w;
    hacc[4] += gv * w1.x; hacc[5] += gv * w1.y; hacc[6] += gv * w1.z; hacc[7] += gv * w1.w;
  }
  #pragma unroll
  for (int j = 0; j < 8; ++j) hid[rg][o0 + j] = tanhf(hacc[j]);
  __syncthreads();

  if (tid < 16 * 8) {
    int lr = tid >> 3, c = tid & 7;
    int gr = row0 + lr;
    float a = eb2[i * 8 + c];
    for (int hh = 0; hh < Hh; ++hh) a += hid[lr][hh] * ew2[((size_t)i * Hh + hh) * 8 + c];
    if (c < ETc) se[((size_t)i * (Bc * Ee) + gr) * ETc + c] = 1.0f / (1.0f + expf(-(a + 2.0f)));
    else         te[((size_t)i * (Bc * Ee) + gr) * ETc + (c - ETc)] = a;
  }
}

// per-element sequential fold over 12 layers + per-b log-jacobian reduction
__global__ __launch_bounds__(256)
void combine_kernel(const float* __restrict__ x_deq, const float* __restrict__ adj_deq,
                    const float* __restrict__ sn, const float* __restrict__ tn,
                    const float* __restrict__ se, const float* __restrict__ te,
                    float* __restrict__ out)
{
  const int b = blockIdx.x, tid = threadIdx.x;
  float ljx = 0.0f, lja = 0.0f;

  for (int j = tid; j < Nn * NTc; j += 256) {
    int n = j / NTc, c = j - n * NTc;
    int row = b * Nn + n;
    float v = x_deq[b * (Nn * NTc) + j];
    #pragma unroll
    for (int i = 0; i < Ll; ++i) {
      float s = sn[((size_t)i * (Bc * Nn) + row) * NTc + c];
      float t = tn[((size_t)i * (Bc * Nn) + row) * NTc + c];
      v = v * s + t;
      ljx += logf(fabsf(s) + 1e-20f);
    }
    out[b * (Nn * NTc) + j] = v;
  }

  for (int j = tid; j < Ee * ETc; j += 256) {
    int e = j / ETc, c = j - e * ETc;
    int row = b * Ee + e;
    float v = adj_deq[b * (Ee * ETc) + j];
    #pragma unroll
    for (int i = 0; i < Ll; ++i) {
      float s = se[((size_t)i * (Bc * Ee) + row) * ETc + c];
      float t = te[((size_t)i * (Bc * Ee) + row) * ETc + c];
      v = v * s + t;
      lja += logf(fabsf(s) + 1e-20f);
    }
    out[Bc * Nn * NTc + b * (Ee * ETc) + j] = v;
  }

  __shared__ float red[256];
  red[tid] = ljx; __syncthreads();
  for (int st = 128; st > 0; st >>= 1) { if (tid < st) red[tid] += red[tid + st]; __syncthreads(); }
  if (tid == 0) out[Bc * Nn * NTc + Bc * Ee * ETc + b] = red[0];
  __syncthreads();
  red[tid] = lja; __syncthreads();
  for (int st = 128; st > 0; st >>= 1) { if (tid < st) red[tid] += red[tid + st]; __syncthreads(); }
  if (tid == 0) out[Bc * Nn * NTc + Bc * Ee * ETc + Bc + b] = red[0];
}

extern "C" void kernel_launch(void* const* d_in, const int* in_sizes, int n_in,
                              void* d_out, int out_size, void* d_ws, size_t ws_size,
                              hipStream_t stream)
{
  const float* x       = (const float*)d_in[0];
  const float* adj     = (const float*)d_in[1];
  const float* x_deq   = (const float*)d_in[2];
  const float* adj_deq = (const float*)d_in[3];
  const void*  mn_src  = d_in[4];
  const void*  me_src  = d_in[5];
  const int*   isel    = (const int*)d_in[6];
  const float* emb_w   = (const float*)d_in[7];
  const float* gw      = (const float*)d_in[8];
  const float* gb      = (const float*)d_in[9];
  const float* nw1     = (const float*)d_in[10];
  const float* nb1     = (const float*)d_in[11];
  const float* nw2     = (const float*)d_in[12];
  const float* nb2     = (const float*)d_in[13];
  const float* ew1     = (const float*)d_in[14];
  const float* eb1     = (const float*)d_in[15];
  const float* ew2     = (const float*)d_in[16];
  const float* eb2     = (const float*)d_in[17];

  char* ws = (char*)d_ws;
  uint8_t* mn  = (uint8_t*)(ws + WS_MN);
  uint8_t* me  = (uint8_t*)(ws + WS_ME);
  float* h0    = (float*)(ws + WS_H0);
  float* Sm    = (float*)(ws + WS_S);
  float* gnode = (float*)(ws + WS_GNODE);
  float* gedge = (float*)(ws + WS_GEDGE);
  float* sn    = (float*)(ws + WS_SN);
  float* tn    = (float*)(ws + WS_TN);
  float* se    = (float*)(ws + WS_SE);
  float* te    = (float*)(ws + WS_TE);

  prep_masks<<<256, 256, 0, stream>>>(mn_src, me_src, mn, me);
  h0_kernel<<<(Bc * Nn * Hh + 255) / 256, 256, 0, stream>>>(x, emb_w, h0);
  s_kernel<<<(Bc * GL * Nn * Hh + 255) / 256, 256, 0, stream>>>(h0, gw, Sm);
  gcn_kernel<<<Bc * Rr, 256, 0, stream>>>(adj, mn, me, Sm, gw, gb, isel, gnode, gedge);
  node_st_kernel<<<Ll * 19, 256, 0, stream>>>(gnode, nw1, nb1, nw2, nb2, sn, tn);
  edge_st_kernel<<<Ll * 189, 256, 0, stream>>>(gedge, ew1, eb1, ew2, eb2, se, te);
  combine_kernel<<<Bc, 256, 0, stream>>>(x_deq, adj_deq, sn, tn, se, te, (float*)d_out);
}

// Round 2
// 507.966 us; speedup vs baseline: 2.7722x; 2.7722x over previous
//
#include <hip/hip_runtime.h>
#include <stdint.h>
#include <math.h>

#define Bc   8
#define Nn   38
#define NTc  9
#define ETc  4
#define Rr   416
#define Ee   378
#define Hh   128
#define Ll   12
#define GL   3

typedef __attribute__((ext_vector_type(8))) short s16x8;
typedef __attribute__((ext_vector_type(4))) short s16x4;
typedef __attribute__((ext_vector_type(4))) float f32x4;

// ---------------- workspace layout (bytes) ----------------
static const size_t WS_MN    = 0;         // 15808 -> pad 15872
static const size_t WS_ME    = 15872;     // 600704 -> 616576
static const size_t WS_H0    = 616576;    // 304*128*4 = 155648 -> 772224
static const size_t WS_ST    = 772224;    // 8*3*128*64*2 = 393216 -> 1165440 (bf16, col-major, m padded to 64 w/ zeros)
static const size_t WS_GWT   = 1165440;   // 9*128*128*2 = 294912 -> 1460352 (bf16 W^T)
static const size_t WS_GNODE = 1460352;   // 304*128*4 = 155648 -> 1616000
static const size_t WS_GEDGE = 1616000;   // 8*378*384*2 = 2322432 -> 3938432 (bf16)
static const size_t WS_SN    = 3938432;   // 131328 -> 4069760
static const size_t WS_TN    = 4069760;   // 131328 -> 4201088
static const size_t WS_SE    = 4201088;   // 580608 -> 4781696
static const size_t WS_TE    = 4781696;   // 580608 -> 5362304

__device__ __forceinline__ unsigned short f2bf(float f) {
  unsigned u = __float_as_uint(f);
  u += 0x7FFFu + ((u >> 16) & 1u);       // RNE
  return (unsigned short)(u >> 16);
}
__device__ __forceinline__ float bf2f(unsigned short h) {
  return __uint_as_float(((unsigned)h) << 16);
}

__device__ __forceinline__ uint8_t mval(const void* src, int i, int mode) {
  if (mode == 0) return ((const int*)src)[i] != 0;
  if (mode == 1) return ((const float*)src)[i] != 0.0f;
  return ((const uint8_t*)src)[i] != 0;
}

__global__ void prep_masks(const void* __restrict__ mn_src, const void* __restrict__ me_src,
                           uint8_t* __restrict__ mn_dst, uint8_t* __restrict__ me_dst)
{
  __shared__ int s01, sf;
  if (threadIdx.x == 0) { s01 = 1; sf = 1; }
  __syncthreads();
  const uint32_t* p = (const uint32_t*)me_src;
  bool a01 = true, af = true;
  for (int i = threadIdx.x; i < 256; i += blockDim.x) {
    uint32_t v = p[i];
    if (v > 1u) a01 = false;
    if (v != 0u && v != 0x3f800000u) af = false;
  }
  if (!a01) atomicAnd(&s01, 0);
  if (!af)  atomicAnd(&sf, 0);
  __syncthreads();
  const int mode = s01 ? 0 : (sf ? 1 : 2);

  const int n_node = Rr * Nn;
  const int n_edge = Rr * Nn * Nn;
  const int tot = n_node + n_edge;
  for (int i = blockIdx.x * blockDim.x + threadIdx.x; i < tot; i += gridDim.x * blockDim.x) {
    if (i < n_node) mn_dst[i] = mval(mn_src, i, mode);
    else            me_dst[i - n_node] = mval(me_src, i - n_node, mode);
  }
}

__global__ void h0_kernel(const float* __restrict__ x, const float* __restrict__ emb_w,
                          float* __restrict__ h0)
{
  int idx = blockIdx.x * blockDim.x + threadIdx.x;
  if (idx >= Bc * Nn * Hh) return;
  int bn = idx >> 7, o = idx & 127;
  float acc = 0.0f;
  #pragma unroll
  for (int i = 0; i < NTc; ++i) acc += x[bn * NTc + i] * emb_w[i * Hh + o];
  h0[idx] = acc;
}

// St[(b*3+e)*128 + col][m(0..63)] = bf16( sum_k h0[b,m,k] * gw[0,e,k,col] ), m>=38 -> 0
__global__ void s_kernel(const float* __restrict__ h0, const float* __restrict__ gw,
                         unsigned short* __restrict__ St)
{
  int idx = blockIdx.x * blockDim.x + threadIdx.x;
  if (idx >= Bc * GL * Hh * 64) return;
  int m = idx & 63;
  int col = (idx >> 6) & 127;
  int t = idx >> 13;              // b*3+e
  int e = t % GL, b = t / GL;
  float acc = 0.0f;
  if (m < Nn)
    for (int k = 0; k < Hh; ++k)
      acc += h0[(b * Nn + m) * Hh + k] * gw[((size_t)e * Hh + k) * Hh + col];
  St[idx] = (m < Nn) ? f2bf(acc) : (unsigned short)0;
}

// gwt[(le*128 + col)*128 + k] = bf16(gw[le, k, col])   (W^T so B-frags are contiguous)
__global__ void wt_kernel(const float* __restrict__ gw, unsigned short* __restrict__ gwt)
{
  int idx = blockIdx.x * blockDim.x + threadIdx.x;
  if (idx >= GL * GL * Hh * Hh) return;
  int k = idx & 127, col = (idx >> 7) & 127, le = idx >> 14;
  gwt[idx] = f2bf(gw[((size_t)le * Hh + k) * Hh + col]);
}

// One block per (b,r). bf16 MFMA GCN: M=48(pad), N=128, K=128 / K=64(pad).
__global__ __launch_bounds__(256, 3)
void gcn_mfma_kernel(const float* __restrict__ adj, const uint8_t* __restrict__ mn,
                     const uint8_t* __restrict__ me, const unsigned short* __restrict__ St,
                     const unsigned short* __restrict__ gwt, const float* __restrict__ gb,
                     const int* __restrict__ isel,
                     float* __restrict__ gnode, unsigned short* __restrict__ gedge)
{
  __shared__ unsigned short h_lds[48 * 128];   // [row][k^((row&7)<<3)]
  __shared__ unsigned short supT[128 * 64];    // [col][k^((col&7)<<3)]  (k = sup row m)
  __shared__ unsigned short am_lds[GL * 48 * 64]; // [e][row][m^((row&7)<<3)]
  __shared__ float ge[128];
  __shared__ unsigned char mnu[64];

  const int tid = threadIdx.x;
  const int b = blockIdx.x / Rr;
  const int r = blockIdx.x - b * Rr;
  const int lane = tid & 63;
  const int wv = tid >> 6;
  const int lo = lane & 15;          // A row / B,D col within tile
  const int q  = lane >> 4;          // k-group (A/B), row-group (D)
  const int swz = (lo & 7) << 3;     // element-XOR for rows/cols == lo (mod 16)
  const int ct0 = 2 * wv;            // this wave's two col-tiles

  // ---- init am (masked adj, zero-padded to 48x64) + node mask ----
  for (int idx = tid; idx < GL * 48 * 64; idx += 256) {
    int e = idx / (48 * 64);
    int rem = idx - e * (48 * 64);
    int n = rem >> 6, m = rem & 63;
    float v = 0.0f;
    if (n < Nn && m < Nn && me[r * (Nn * Nn) + n * Nn + m])
      v = adj[((b * ETc + e) * Nn + n) * Nn + m];
    am_lds[e * 3072 + n * 64 + (m ^ ((n & 7) << 3))] = f2bf(v);
  }
  if (tid < 64) mnu[tid] = (tid < Nn) ? mn[r * Nn + tid] : 0;
  __syncthreads();

  f32x4 outacc[3][2];

  for (int l = 0; l < GL; ++l) {
    // bias init (bias depends only on output col)
    #pragma unroll
    for (int ci = 0; ci < 2; ++ci) {
      float bias = gb[l * Hh + 16 * (ct0 + ci) + lo];
      f32x4 bv = {bias, bias, bias, bias};
      outacc[0][ci] = bv; outacc[1][ci] = bv; outacc[2][ci] = bv;
    }

    for (int e = 0; e < GL; ++e) {
      if (l == 0) {
        // stage node-masked S^T[b,e] into supT
        __syncthreads();                      // prior supT readers done
        {
          int scol = tid >> 1, skh = (tid & 1) * 32;
          const unsigned short* ssrc = St + ((size_t)(b * GL + e) * 128 + scol) * 64 + skh;
          int sswz = (scol & 7) << 3;
          #pragma unroll
          for (int j = 0; j < 4; ++j) {
            s16x8 v = *(const s16x8*)(ssrc + 8 * j);
            #pragma unroll
            for (int i = 0; i < 8; ++i)
              if (!mnu[skh + 8 * j + i]) v[i] = 0;
            *(s16x8*)&supT[scol * 64 + ((skh + 8 * j) ^ sswz)] = v;
          }
        }
        __syncthreads();
      } else {
        // GEMM1: sup = h @ W[l,e]   (M=48, N=128, K=128)
        f32x4 sa[3][2];
        #pragma unroll
        for (int rt = 0; rt < 3; ++rt)
          #pragma unroll
          for (int ci = 0; ci < 2; ++ci)
            sa[rt][ci] = (f32x4){0.f, 0.f, 0.f, 0.f};

        const unsigned short* wb = gwt + (size_t)(l * GL + e) * (Hh * Hh);
        #pragma unroll
        for (int ks = 0; ks < 4; ++ks) {
          int k0 = 8 * q + 32 * ks;
          s16x8 b0 = *(const s16x8*)(wb + (16 * ct0 + lo) * 128 + k0);
          s16x8 b1 = *(const s16x8*)(wb + (16 * ct0 + 16 + lo) * 128 + k0);
          #pragma unroll
          for (int rt = 0; rt < 3; ++rt) {
            int row = lo + 16 * rt;
            s16x8 a = *(const s16x8*)&h_lds[row * 128 + (k0 ^ swz)];
            sa[rt][0] = __builtin_amdgcn_mfma_f32_16x16x32_bf16(a, b0, sa[rt][0], 0, 0, 0);
            sa[rt][1] = __builtin_amdgcn_mfma_f32_16x16x32_bf16(a, b1, sa[rt][1], 0, 0, 0);
          }
        }
        __syncthreads();                      // prior supT readers done
        // write D-frags -> supT (col-major, 4 consecutive k per 8B write)
        #pragma unroll
        for (int rt = 0; rt < 3; ++rt)
          #pragma unroll
          for (int ci = 0; ci < 2; ++ci) {
            int col = 16 * (ct0 + ci) + lo;
            s16x4 pk;
            #pragma unroll
            for (int j = 0; j < 4; ++j) pk[j] = (short)f2bf(sa[rt][ci][j]);
            int k0 = 16 * rt + 4 * q;
            *(s16x4*)&supT[col * 64 + (k0 ^ swz)] = pk;
          }
        __syncthreads();
      }

      // GEMM2: out += am[e] @ sup   (K = 64 padded)
      #pragma unroll
      for (int ks = 0; ks < 2; ++ks) {
        int k0 = 8 * q + 32 * ks;
        s16x8 b0 = *(const s16x8*)&supT[(16 * ct0 + lo) * 64 + (k0 ^ swz)];
        s16x8 b1 = *(const s16x8*)&supT[(16 * ct0 + 16 + lo) * 64 + (k0 ^ swz)];
        #pragma unroll
        for (int rt = 0; rt < 3; ++rt) {
          int row = lo + 16 * rt;
          s16x8 a = *(const s16x8*)&am_lds[e * 3072 + row * 64 + (k0 ^ swz)];
          outacc[rt][0] = __builtin_amdgcn_mfma_f32_16x16x32_bf16(a, b0, outacc[rt][0], 0, 0, 0);
          outacc[rt][1] = __builtin_amdgcn_mfma_f32_16x16x32_bf16(a, b1, outacc[rt][1], 0, 0, 0);
        }
      }
    }

    // write h for next layer (relu except last); GEMM2 never reads h -> safe pre-barrier
    #pragma unroll
    for (int rt = 0; rt < 3; ++rt)
      #pragma unroll
      for (int ci = 0; ci < 2; ++ci) {
        int col = 16 * (ct0 + ci) + lo;
        #pragma unroll
        for (int j = 0; j < 4; ++j) {
          int row = 16 * rt + 4 * q + j;
          float v = outacc[rt][ci][j];
          if (l < GL - 1) v = fmaxf(v, 0.0f);
          h_lds[row * 128 + (col ^ ((row & 7) << 3))] = f2bf(v);
        }
      }
    __syncthreads();
  }

  // ---- epilogue: graph_emb + outputs ----
  if (tid < 128) {
    float s = 0.0f;
    for (int n = 0; n < Nn; ++n)
      s += bf2f(h_lds[n * 128 + (tid ^ ((n & 7) << 3))]);
    ge[tid] = s;
  }
  __syncthreads();

  if (r < Nn) {
    if (tid < 128) gnode[(size_t)(b * Nn + r) * Hh + tid] = ge[tid];
  } else {
    int ei = r - Nn;
    int i0 = isel[2 * ei], i1 = isel[2 * ei + 1];
    unsigned short* dst = gedge + (size_t)(b * Ee + ei) * 384;
    if (tid < 128) {
      dst[tid]        = h_lds[i0 * 128 + (tid ^ ((i0 & 7) << 3))];
      dst[128 + tid]  = h_lds[i1 * 128 + (tid ^ ((i1 & 7) << 3))];
      dst[256 + tid]  = f2bf(ge[tid]);
    }
  }
}

__global__ __launch_bounds__(256)
void node_st_kernel(const float* __restrict__ gnode, const float* __restrict__ nw1,
                    const float* __restrict__ nb1, const float* __restrict__ nw2,
                    const float* __restrict__ nb2,
                    float* __restrict__ sn, float* __restrict__ tn)
{
  __shared__ float gbuf[16][132];
  __shared__ float hid[16][132];
  const int tid = threadIdx.x;
  const int i = blockIdx.x / 19;
  const int tile = blockIdx.x - i * 19;
  const int row0 = tile * 16;

  for (int idx = tid; idx < 16 * Hh; idx += 256) {
    int lr = idx >> 7, c = idx & 127;
    gbuf[lr][c] = gnode[(size_t)(row0 + lr) * Hh + c];
  }
  __syncthreads();

  const int og = tid & 15, rg = tid >> 4, o0 = og * 8;
  float hacc[8];
  #pragma unroll
  for (int j = 0; j < 8; ++j) hacc[j] = nb1[i * Hh + o0 + j];
  for (int k = 0; k < Hh; ++k) {
    const float* wp = &nw1[((size_t)i * Hh + k) * Hh + o0];
    float4 w0 = *(const float4*)wp;
    float4 w1 = *(const float4*)(wp + 4);
    float gv = gbuf[rg][k];
    hacc[0] += gv * w0.x; hacc[1] += gv * w0.y; hacc[2] += gv * w0.z; hacc[3] += gv * w0.w;
    hacc[4] += gv * w1.x; hacc[5] += gv * w1.y; hacc[6] += gv * w1.z; hacc[7] += gv * w1.w;
  }
  #pragma unroll
  for (int j = 0; j < 8; ++j) hid[rg][o0 + j] = tanhf(hacc[j]);
  __syncthreads();

  for (int idx = tid; idx < 16 * 18; idx += 256) {
    int lr = idx / 18, c = idx - lr * 18;
    int gr = row0 + lr;
    float a = nb2[i * 18 + c];
    for (int hh = 0; hh < Hh; ++hh) a += hid[lr][hh] * nw2[((size_t)i * Hh + hh) * 18 + c];
    if (c < NTc) sn[((size_t)i * (Bc * Nn) + gr) * NTc + c] = 1.0f / (1.0f + expf(-(a + 2.0f)));
    else         tn[((size_t)i * (Bc * Nn) + gr) * NTc + (c - NTc)] = a;
  }
}

__global__ __launch_bounds__(256)
void edge_st_kernel(const unsigned short* __restrict__ gedge, const float* __restrict__ ew1,
                    const float* __restrict__ eb1, const float* __restrict__ ew2,
                    const float* __restrict__ eb2,
                    float* __restrict__ se, float* __restrict__ te)
{
  __shared__ float gbuf[16][388];
  __shared__ float hid[16][132];
  const int tid = threadIdx.x;
  const int i = blockIdx.x / 189;
  const int tile = blockIdx.x - i * 189;
  const int row0 = tile * 16;

  for (int j = tid; j < 16 * 192; j += 256) {     // 2 bf16 per u32
    int lr = j / 192, c2 = j - lr * 192;
    const uint32_t* gp = (const uint32_t*)(gedge + (size_t)(row0 + lr) * 384);
    uint32_t u = gp[c2];
    gbuf[lr][2 * c2]     = __uint_as_float(u << 16);
    gbuf[lr][2 * c2 + 1] = __uint_as_float(u & 0xffff0000u);
  }
  __syncthreads();

  const int og = tid & 15, rg = tid >> 4, o0 = og * 8;
  float hacc[8];
  #pragma unroll
  for (int j = 0; j < 8; ++j) hacc[j] = eb1[i * Hh + o0 + j];
  for (int k = 0; k < 384; ++k) {
    const float* wp = &ew1[((size_t)i * 384 + k) * Hh + o0];
    float4 w0 = *(const float4*)wp;
    float4 w1 = *(const float4*)(wp + 4);
    float gv = gbuf[rg][k];
    hacc[0] += gv * w0.x; hacc[1] += gv * w0.y; hacc[2] += gv * w0.z; hacc[3] += gv * w0.w;
    hacc[4] += gv * w1.x; hacc[5] += gv * w1.y; hacc[6] += gv * w1.z; hacc[7] += gv * w1.w;
  }
  #pragma unroll
  for (int j = 0; j < 8; ++j) hid[rg][o0 + j] = tanhf(hacc[j]);
  __syncthreads();

  if (tid < 16 * 8) {
    int lr = tid >> 3, c = tid & 7;
    int gr = row0 + lr;
    float a = eb2[i * 8 + c];
    for (int hh = 0; hh < Hh; ++hh) a += hid[lr][hh] * ew2[((size_t)i * Hh + hh) * 8 + c];
    if (c < ETc) se[((size_t)i * (Bc * Ee) + gr) * ETc + c] = 1.0f / (1.0f + expf(-(a + 2.0f)));
    else         te[((size_t)i * (Bc * Ee) + gr) * ETc + (c - ETc)] = a;
  }
}

__global__ __launch_bounds__(256)
void combine_kernel(const float* __restrict__ x_deq, const float* __restrict__ adj_deq,
                    const float* __restrict__ sn, const float* __restrict__ tn,
                    const float* __restrict__ se, const float* __restrict__ te,
                    float* __restrict__ out)
{
  const int b = blockIdx.x, tid = threadIdx.x;
  float ljx = 0.0f, lja = 0.0f;

  for (int j = tid; j < Nn * NTc; j += 256) {
    int n = j / NTc, c = j - n * NTc;
    int row = b * Nn + n;
    float v = x_deq[b * (Nn * NTc) + j];
    #pragma unroll
    for (int i = 0; i < Ll; ++i) {
      float s = sn[((size_t)i * (Bc * Nn) + row) * NTc + c];
      float t = tn[((size_t)i * (Bc * Nn) + row) * NTc + c];
      v = v * s + t;
      ljx += logf(fabsf(s) + 1e-20f);
    }
    out[b * (Nn * NTc) + j] = v;
  }

  for (int j = tid; j < Ee * ETc; j += 256) {
    int e = j / ETc, c = j - e * ETc;
    int row = b * Ee + e;
    float v = adj_deq[b * (Ee * ETc) + j];
    #pragma unroll
    for (int i = 0; i < Ll; ++i) {
      float s = se[((size_t)i * (Bc * Ee) + row) * ETc + c];
      float t = te[((size_t)i * (Bc * Ee) + row) * ETc + c];
      v = v * s + t;
      lja += logf(fabsf(s) + 1e-20f);
    }
    out[Bc * Nn * NTc + b * (Ee * ETc) + j] = v;
  }

  __shared__ float red[256];
  red[tid] = ljx; __syncthreads();
  for (int st = 128; st > 0; st >>= 1) { if (tid < st) red[tid] += red[tid + st]; __syncthreads(); }
  if (tid == 0) out[Bc * Nn * NTc + Bc * Ee * ETc + b] = red[0];
  __syncthreads();
  red[tid] = lja; __syncthreads();
  for (int st = 128; st > 0; st >>= 1) { if (tid < st) red[tid] += red[tid + st]; __syncthreads(); }
  if (tid == 0) out[Bc * Nn * NTc + Bc * Ee * ETc + Bc + b] = red[0];
}

extern "C" void kernel_launch(void* const* d_in, const int* in_sizes, int n_in,
                              void* d_out, int out_size, void* d_ws, size_t ws_size,
                              hipStream_t stream)
{
  const float* x       = (const float*)d_in[0];
  const float* adj     = (const float*)d_in[1];
  const float* x_deq   = (const float*)d_in[2];
  const float* adj_deq = (const float*)d_in[3];
  const void*  mn_src  = d_in[4];
  const void*  me_src  = d_in[5];
  const int*   isel    = (const int*)d_in[6];
  const float* emb_w   = (const float*)d_in[7];
  const float* gw      = (const float*)d_in[8];
  const float* gb      = (const float*)d_in[9];
  const float* nw1     = (const float*)d_in[10];
  const float* nb1     = (const float*)d_in[11];
  const float* nw2     = (const float*)d_in[12];
  const float* nb2     = (const float*)d_in[13];
  const float* ew1     = (const float*)d_in[14];
  const float* eb1     = (const float*)d_in[15];
  const float* ew2     = (const float*)d_in[16];
  const float* eb2     = (const float*)d_in[17];

  char* ws = (char*)d_ws;
  uint8_t* mn            = (uint8_t*)(ws + WS_MN);
  uint8_t* me            = (uint8_t*)(ws + WS_ME);
  float* h0              = (float*)(ws + WS_H0);
  unsigned short* St     = (unsigned short*)(ws + WS_ST);
  unsigned short* gwt    = (unsigned short*)(ws + WS_GWT);
  float* gnode           = (float*)(ws + WS_GNODE);
  unsigned short* gedge  = (unsigned short*)(ws + WS_GEDGE);
  float* sn              = (float*)(ws + WS_SN);
  float* tn              = (float*)(ws + WS_TN);
  float* se              = (float*)(ws + WS_SE);
  float* te              = (float*)(ws + WS_TE);

  prep_masks<<<256, 256, 0, stream>>>(mn_src, me_src, mn, me);
  h0_kernel<<<(Bc * Nn * Hh + 255) / 256, 256, 0, stream>>>(x, emb_w, h0);
  s_kernel<<<(Bc * GL * Hh * 64 + 255) / 256, 256, 0, stream>>>(h0, gw, St);
  wt_kernel<<<(GL * GL * Hh * Hh + 255) / 256, 256, 0, stream>>>(gw, gwt);
  gcn_mfma_kernel<<<Bc * Rr, 256, 0, stream>>>(adj, mn, me, St, gwt, gb, isel, gnode, gedge);
  node_st_kernel<<<Ll * 19, 256, 0, stream>>>(gnode, nw1, nb1, nw2, nb2, sn, tn);
  edge_st_kernel<<<Ll * 189, 256, 0, stream>>>(gedge, ew1, eb1, ew2, eb2, se, te);
  combine_kernel<<<Bc, 256, 0, stream>>>(x_deq, adj_deq, sn, tn, se, te, (float*)d_out);
}

// Round 7
// 337.838 us; speedup vs baseline: 4.1682x; 1.5036x over previous
//
#include <hip/hip_runtime.h>
#include <stdint.h>
#include <math.h>

#define Bc   8
#define Nn   38
#define NTc  9
#define ETc  4
#define Rr   416
#define Ee   378
#define Hh   128
#define Ll   12
#define GL   3

typedef __attribute__((ext_vector_type(8))) short s16x8;
typedef __attribute__((ext_vector_type(4))) short s16x4;
typedef __attribute__((ext_vector_type(4))) float f32x4;

// ---------------- workspace layout (bytes) ----------------
static const size_t WS_MN    = 0;         // 15808 -> 15872
static const size_t WS_ME    = 15872;     // 600704 -> 616576
static const size_t WS_H0    = 616576;    // 155648 -> 772224
static const size_t WS_ST    = 772224;    // 393216 -> 1165440 (bf16 S^T, m pad 64)
static const size_t WS_GWT   = 1165440;   // 294912 -> 1460352 (bf16 gc W^T)
static const size_t WS_NWT   = 1460352;   // 393216 -> 1853568 (bf16 nw1^T)
static const size_t WS_EWT   = 1853568;   // 1179648 -> 3033216 (bf16 ew1^T)
static const size_t WS_GNB   = 3033216;   // 304*128*2 = 77824 -> 3111040 (bf16 gnode)
static const size_t WS_GEDGE = 3111040;   // 2322432 -> 5433472 (bf16)
static const size_t WS_SN    = 5433472;   // 131328 -> 5564800
static const size_t WS_TN    = 5564800;   // 131328 -> 5696128
static const size_t WS_SE    = 5696128;   // 580608 -> 6276736
static const size_t WS_TE    = 6276736;   // 580608 -> 6857344
static const size_t WS_PART  = 6857344;   // 512 -> 6857856

__device__ __forceinline__ unsigned short f2bf(float f) {
  unsigned u = __float_as_uint(f);
  u += 0x7FFFu + ((u >> 16) & 1u);       // RNE
  return (unsigned short)(u >> 16);
}
__device__ __forceinline__ float bf2f(unsigned short h) {
  return __uint_as_float(((unsigned)h) << 16);
}

__device__ __forceinline__ uint8_t mval(const void* src, int i, int mode) {
  if (mode == 0) return ((const int*)src)[i] != 0;
  if (mode == 1) return ((const float*)src)[i] != 0.0f;
  return ((const uint8_t*)src)[i] != 0;
}

__global__ void prep_masks(const void* __restrict__ mn_src, const void* __restrict__ me_src,
                           uint8_t* __restrict__ mn_dst, uint8_t* __restrict__ me_dst)
{
  __shared__ int s01, sf;
  if (threadIdx.x == 0) { s01 = 1; sf = 1; }
  __syncthreads();
  const uint32_t* p = (const uint32_t*)me_src;
  bool a01 = true, af = true;
  for (int i = threadIdx.x; i < 256; i += blockDim.x) {
    uint32_t v = p[i];
    if (v > 1u) a01 = false;
    if (v != 0u && v != 0x3f800000u) af = false;
  }
  if (!a01) atomicAnd(&s01, 0);
  if (!af)  atomicAnd(&sf, 0);
  __syncthreads();
  const int mode = s01 ? 0 : (sf ? 1 : 2);

  const int n_node = Rr * Nn;
  const int n_edge = Rr * Nn * Nn;
  const int tot = n_node + n_edge;
  for (int i = blockIdx.x * blockDim.x + threadIdx.x; i < tot; i += gridDim.x * blockDim.x) {
    if (i < n_node) mn_dst[i] = mval(mn_src, i, mode);
    else            me_dst[i - n_node] = mval(me_src, i - n_node, mode);
  }
}

// transpose+cast all three W1-style weight tensors to bf16 [..][col][k]
__global__ void prep_weights(const float* __restrict__ gw, const float* __restrict__ nw1,
                             const float* __restrict__ ew1,
                             unsigned short* __restrict__ gwt, unsigned short* __restrict__ nwt,
                             unsigned short* __restrict__ ewt)
{
  const int NG = 9 * 128 * 128;     // 147456
  const int NNw = 12 * 128 * 128;   // 196608
  const int NEw = 12 * 128 * 384;   // 589824
  int idx = blockIdx.x * blockDim.x + threadIdx.x;
  if (idx < NG) {
    int k = idx & 127, col = (idx >> 7) & 127, le = idx >> 14;
    gwt[idx] = f2bf(gw[((size_t)le * 128 + k) * 128 + col]);
  } else if (idx < NG + NNw) {
    int j = idx - NG;
    int k = j & 127, col = (j >> 7) & 127, i = j >> 14;
    nwt[j] = f2bf(nw1[((size_t)i * 128 + k) * 128 + col]);
  } else if (idx < NG + NNw + NEw) {
    int j = idx - NG - NNw;
    int k = j % 384; int rem = j / 384;
    int col = rem & 127, i = rem >> 7;
    ewt[j] = f2bf(ew1[((size_t)i * 384 + k) * 128 + col]);
  }
}

__global__ void h0_kernel(const float* __restrict__ x, const float* __restrict__ emb_w,
                          float* __restrict__ h0)
{
  int idx = blockIdx.x * blockDim.x + threadIdx.x;
  if (idx >= Bc * Nn * Hh) return;
  int bn = idx >> 7, o = idx & 127;
  float acc = 0.0f;
  #pragma unroll
  for (int i = 0; i < NTc; ++i) acc += x[bn * NTc + i] * emb_w[i * Hh + o];
  h0[idx] = acc;
}

// St[(b*3+e)*128 + col][m(0..63)] = bf16( sum_k h0[b,m,k] * gw[0,e,k,col] ), m>=38 -> 0
__global__ void s_kernel(const float* __restrict__ h0, const float* __restrict__ gw,
                         unsigned short* __restrict__ St)
{
  int idx = blockIdx.x * blockDim.x + threadIdx.x;
  if (idx >= Bc * GL * Hh * 64) return;
  int m = idx & 63;
  int col = (idx >> 6) & 127;
  int t = idx >> 13;              // b*3+e
  int e = t % GL, b = t / GL;
  float acc = 0.0f;
  if (m < Nn)
    for (int k = 0; k < Hh; ++k)
      acc += h0[(b * Nn + m) * Hh + k] * gw[((size_t)e * Hh + k) * Hh + col];
  St[idx] = (m < Nn) ? f2bf(acc) : (unsigned short)0;
}

// One block per (b,r). bf16 MFMA GCN: M=48(pad), N=128, K=128 / K=64(pad).
__global__ __launch_bounds__(256, 3)
void gcn_mfma_kernel(const float* __restrict__ adj, const uint8_t* __restrict__ mn,
                     const uint8_t* __restrict__ me, const unsigned short* __restrict__ St,
                     const unsigned short* __restrict__ gwt, const float* __restrict__ gb,
                     const int* __restrict__ isel,
                     unsigned short* __restrict__ gnb, unsigned short* __restrict__ gedge)
{
  // merged LDS: avoid inter-array padding (was reported 57KB -> 2 blocks/CU)
  __shared__ char smem[47744];
  unsigned short* h_lds  = (unsigned short*)smem;             // 48*128*2 = 12288
  unsigned short* supT   = (unsigned short*)(smem + 12288);   // 128*64*2 = 16384
  unsigned short* am_lds = (unsigned short*)(smem + 28672);   // 3*48*64*2 = 18432
  float*          ge     = (float*)(smem + 47104);            // 512
  unsigned char*  mnu    = (unsigned char*)(smem + 47616);    // 64

  const int tid = threadIdx.x;
  const int b = blockIdx.x / Rr;
  const int r = blockIdx.x - b * Rr;
  const int lane = tid & 63;
  const int wv = tid >> 6;
  const int lo = lane & 15;          // A row / B,D col within tile
  const int q  = lane >> 4;          // k-group (A/B), row-group (D)
  const int swz = (lo & 7) << 3;     // element-XOR for rows/cols == lo (mod 16)
  const int ct0 = 2 * wv;            // this wave's two col-tiles

  // ---- init am (masked adj, zero-padded to 48x64) + node mask ----
  for (int idx = tid; idx < GL * 48 * 64; idx += 256) {
    int e = idx / (48 * 64);
    int rem = idx - e * (48 * 64);
    int n = rem >> 6, m = rem & 63;
    float v = 0.0f;
    if (n < Nn && m < Nn && me[r * (Nn * Nn) + n * Nn + m])
      v = adj[((b * ETc + e) * Nn + n) * Nn + m];
    am_lds[e * 3072 + n * 64 + (m ^ ((n & 7) << 3))] = f2bf(v);
  }
  if (tid < 64) mnu[tid] = (tid < Nn) ? mn[r * Nn + tid] : 0;
  __syncthreads();

  f32x4 outacc[3][2];

  for (int l = 0; l < GL; ++l) {
    #pragma unroll
    for (int ci = 0; ci < 2; ++ci) {
      float bias = gb[l * Hh + 16 * (ct0 + ci) + lo];
      f32x4 bv = {bias, bias, bias, bias};
      outacc[0][ci] = bv; outacc[1][ci] = bv; outacc[2][ci] = bv;
    }

    for (int e = 0; e < GL; ++e) {
      if (l == 0) {
        __syncthreads();                      // prior supT readers done
        {
          int scol = tid >> 1, skh = (tid & 1) * 32;
          const unsigned short* ssrc = St + ((size_t)(b * GL + e) * 128 + scol) * 64 + skh;
          int sswz = (scol & 7) << 3;
          #pragma unroll
          for (int j = 0; j < 4; ++j) {
            s16x8 v = *(const s16x8*)(ssrc + 8 * j);
            #pragma unroll
            for (int i = 0; i < 8; ++i)
              if (!mnu[skh + 8 * j + i]) v[i] = 0;
            *(s16x8*)&supT[scol * 64 + ((skh + 8 * j) ^ sswz)] = v;
          }
        }
        __syncthreads();
      } else {
        // GEMM1: sup = h @ W[l,e]   (M=48, N=128, K=128)
        f32x4 sa[3][2];
        #pragma unroll
        for (int rt = 0; rt < 3; ++rt)
          #pragma unroll
          for (int ci = 0; ci < 2; ++ci)
            sa[rt][ci] = (f32x4){0.f, 0.f, 0.f, 0.f};

        const unsigned short* wb = gwt + (size_t)(l * GL + e) * (Hh * Hh);
        #pragma unroll
        for (int ks = 0; ks < 4; ++ks) {
          int k0 = 8 * q + 32 * ks;
          s16x8 b0 = *(const s16x8*)(wb + (16 * ct0 + lo) * 128 + k0);
          s16x8 b1 = *(const s16x8*)(wb + (16 * ct0 + 16 + lo) * 128 + k0);
          #pragma unroll
          for (int rt = 0; rt < 3; ++rt) {
            int row = lo + 16 * rt;
            s16x8 a = *(const s16x8*)&h_lds[row * 128 + (k0 ^ swz)];
            sa[rt][0] = __builtin_amdgcn_mfma_f32_16x16x32_bf16(a, b0, sa[rt][0], 0, 0, 0);
            sa[rt][1] = __builtin_amdgcn_mfma_f32_16x16x32_bf16(a, b1, sa[rt][1], 0, 0, 0);
          }
        }
        __syncthreads();                      // prior supT readers done
        #pragma unroll
        for (int rt = 0; rt < 3; ++rt)
          #pragma unroll
          for (int ci = 0; ci < 2; ++ci) {
            int col = 16 * (ct0 + ci) + lo;
            s16x4 pk;
            #pragma unroll
            for (int j = 0; j < 4; ++j) pk[j] = (short)f2bf(sa[rt][ci][j]);
            int k0 = 16 * rt + 4 * q;
            *(s16x4*)&supT[col * 64 + (k0 ^ swz)] = pk;
          }
        __syncthreads();
      }

      // GEMM2: out += am[e] @ sup   (K = 64 padded)
      #pragma unroll
      for (int ks = 0; ks < 2; ++ks) {
        int k0 = 8 * q + 32 * ks;
        s16x8 b0 = *(const s16x8*)&supT[(16 * ct0 + lo) * 64 + (k0 ^ swz)];
        s16x8 b1 = *(const s16x8*)&supT[(16 * ct0 + 16 + lo) * 64 + (k0 ^ swz)];
        #pragma unroll
        for (int rt = 0; rt < 3; ++rt) {
          int row = lo + 16 * rt;
          s16x8 a = *(const s16x8*)&am_lds[e * 3072 + row * 64 + (k0 ^ swz)];
          outacc[rt][0] = __builtin_amdgcn_mfma_f32_16x16x32_bf16(a, b0, outacc[rt][0], 0, 0, 0);
          outacc[rt][1] = __builtin_amdgcn_mfma_f32_16x16x32_bf16(a, b1, outacc[rt][1], 0, 0, 0);
        }
      }
    }

    // write h for next layer (relu except last)
    #pragma unroll
    for (int rt = 0; rt < 3; ++rt)
      #pragma unroll
      for (int ci = 0; ci < 2; ++ci) {
        int col = 16 * (ct0 + ci) + lo;
        #pragma unroll
        for (int j = 0; j < 4; ++j) {
          int row = 16 * rt + 4 * q + j;
          float v = outacc[rt][ci][j];
          if (l < GL - 1) v = fmaxf(v, 0.0f);
          h_lds[row * 128 + (col ^ ((row & 7) << 3))] = f2bf(v);
        }
      }
    __syncthreads();
  }

  // ---- epilogue: graph_emb + outputs ----
  if (tid < 128) {
    float s = 0.0f;
    for (int n = 0; n < Nn; ++n)
      s += bf2f(h_lds[n * 128 + (tid ^ ((n & 7) << 3))]);
    ge[tid] = s;
  }
  __syncthreads();

  if (r < Nn) {
    if (tid < 128) gnb[(size_t)(b * Nn + r) * Hh + tid] = f2bf(ge[tid]);
  } else {
    int ei = r - Nn;
    int i0 = isel[2 * ei], i1 = isel[2 * ei + 1];
    unsigned short* dst = gedge + (size_t)(b * Ee + ei) * 384;
    if (tid < 128) {
      dst[tid]        = h_lds[i0 * 128 + (tid ^ ((i0 & 7) << 3))];
      dst[128 + tid]  = h_lds[i1 * 128 + (tid ^ ((i1 & 7) << 3))];
      dst[256 + tid]  = f2bf(ge[tid]);
    }
  }
}

// ST MLP via MFMA: A [ROWS][IN_W] bf16, wt [12][128][IN_W] bf16, out s/t [12][ROWS][OUT_D]
template<int IN_W, int OUT_D, int ROWS>
__global__ __launch_bounds__(256)
void st_mfma_kernel(const unsigned short* __restrict__ A,
                    const unsigned short* __restrict__ wt,
                    const float* __restrict__ b1,
                    const float* __restrict__ w2,
                    const float* __restrict__ b2,
                    float* __restrict__ s_out, float* __restrict__ t_out)
{
  constexpr int MT = (ROWS + 31) / 32;
  constexpr int OD2 = 2 * OUT_D;
  __shared__ unsigned short hid[32 * 136];
  const int tid = threadIdx.x;
  const int i = blockIdx.x / MT;
  const int mt = blockIdx.x - i * MT;
  const int row0 = mt * 32;
  const int lane = tid & 63, wv = tid >> 6;
  const int lo = lane & 15, q = lane >> 4;

  f32x4 acc[2][2];
  #pragma unroll
  for (int rt = 0; rt < 2; ++rt)
    #pragma unroll
    for (int ci = 0; ci < 2; ++ci)
      acc[rt][ci] = (f32x4){0.f, 0.f, 0.f, 0.f};

  int ra = row0 + lo;       if (ra >= ROWS) ra = 0;
  int rb = row0 + 16 + lo;  if (rb >= ROWS) rb = 0;
  const unsigned short* Ap0 = A + (size_t)ra * IN_W;
  const unsigned short* Ap1 = A + (size_t)rb * IN_W;
  const unsigned short* Bp0 = wt + ((size_t)i * 128 + 32 * wv + lo) * IN_W;
  const unsigned short* Bp1 = wt + ((size_t)i * 128 + 32 * wv + 16 + lo) * IN_W;

  #pragma unroll
  for (int ks = 0; ks < IN_W / 32; ++ks) {
    int k0 = 8 * q + 32 * ks;
    s16x8 a0 = *(const s16x8*)(Ap0 + k0);
    s16x8 a1 = *(const s16x8*)(Ap1 + k0);
    s16x8 b0 = *(const s16x8*)(Bp0 + k0);
    s16x8 b1 = *(const s16x8*)(Bp1 + k0);
    acc[0][0] = __builtin_amdgcn_mfma_f32_16x16x32_bf16(a0, b0, acc[0][0], 0, 0, 0);
    acc[0][1] = __builtin_amdgcn_mfma_f32_16x16x32_bf16(a0, b1, acc[0][1], 0, 0, 0);
    acc[1][0] = __builtin_amdgcn_mfma_f32_16x16x32_bf16(a1, b0, acc[1][0], 0, 0, 0);
    acc[1][1] = __builtin_amdgcn_mfma_f32_16x16x32_bf16(a1, b1, acc[1][1], 0, 0, 0);
  }

  #pragma unroll
  for (int rt = 0; rt < 2; ++rt)
    #pragma unroll
    for (int ci = 0; ci < 2; ++ci) {
      int col = 32 * wv + 16 * ci + lo;
      float bb = b1[i * 128 + col];
      #pragma unroll
      for (int j = 0; j < 4; ++j) {
        int row = 16 * rt + 4 * q + j;
        hid[row * 136 + col] = f2bf(tanhf(acc[rt][ci][j] + bb));
      }
    }
  __syncthreads();

  for (int idx = tid; idx < 32 * OD2; idx += 256) {
    int lr = idx / OD2, c = idx - lr * OD2;
    int gr = row0 + lr;
    if (gr < ROWS) {
      float a = b2[i * OD2 + c];
      for (int k = 0; k < 128; ++k)
        a += bf2f(hid[lr * 136 + k]) * w2[((size_t)i * 128 + k) * OD2 + c];
      if (c < OUT_D) s_out[((size_t)i * ROWS + gr) * OUT_D + c] = 1.0f / (1.0f + expf(-(a + 2.0f)));
      else           t_out[((size_t)i * ROWS + gr) * OUT_D + (c - OUT_D)] = a;
    }
  }
}

// per-element 12-layer fold + partial log-jacobians (8 chunks per b)
__global__ __launch_bounds__(256)
void combine_part(const float* __restrict__ x_deq, const float* __restrict__ adj_deq,
                  const float* __restrict__ sn, const float* __restrict__ tn,
                  const float* __restrict__ se, const float* __restrict__ te,
                  float* __restrict__ out, float* __restrict__ partials)
{
  const int blk = blockIdx.x, tid = threadIdx.x;
  const int b = blk >> 3, ch = blk & 7;
  float ljx = 0.0f, lja = 0.0f;

  for (int j = ch * 256 + tid; j < Nn * NTc; j += 2048) {
    int n = j / NTc, c = j - n * NTc;
    int row = b * Nn + n;
    float v = x_deq[b * (Nn * NTc) + j];
    #pragma unroll
    for (int i = 0; i < Ll; ++i) {
      float s = sn[((size_t)i * (Bc * Nn) + row) * NTc + c];
      float t = tn[((size_t)i * (Bc * Nn) + row) * NTc + c];
      v = v * s + t;
      ljx += logf(fabsf(s) + 1e-20f);
    }
    out[b * (Nn * NTc) + j] = v;
  }

  for (int j = ch * 256 + tid; j < Ee * ETc; j += 2048) {
    int e = j / ETc, c = j - e * ETc;
    int row = b * Ee + e;
    float v = adj_deq[b * (Ee * ETc) + j];
    #pragma unroll
    for (int i = 0; i < Ll; ++i) {
      float s = se[((size_t)i * (Bc * Ee) + row) * ETc + c];
      float t = te[((size_t)i * (Bc * Ee) + row) * ETc + c];
      v = v * s + t;
      lja += logf(fabsf(s) + 1e-20f);
    }
    out[Bc * Nn * NTc + b * (Ee * ETc) + j] = v;
  }

  __shared__ float red[256];
  red[tid] = ljx; __syncthreads();
  for (int st = 128; st > 0; st >>= 1) { if (tid < st) red[tid] += red[tid + st]; __syncthreads(); }
  if (tid == 0) partials[blk] = red[0];
  __syncthreads();
  red[tid] = lja; __syncthreads();
  for (int st = 128; st > 0; st >>= 1) { if (tid < st) red[tid] += red[tid + st]; __syncthreads(); }
  if (tid == 0) partials[64 + blk] = red[0];
}

__global__ void combine_lj(const float* __restrict__ partials, float* __restrict__ out)
{
  int tid = threadIdx.x;
  if (tid < Bc) {
    float sx = 0.0f, sa = 0.0f;
    #pragma unroll
    for (int ch = 0; ch < 8; ++ch) {
      sx += partials[tid * 8 + ch];
      sa += partials[64 + tid * 8 + ch];
    }
    out[Bc * Nn * NTc + Bc * Ee * ETc + tid] = sx;
    out[Bc * Nn * NTc + Bc * Ee * ETc + Bc + tid] = sa;
  }
}

extern "C" void kernel_launch(void* const* d_in, const int* in_sizes, int n_in,
                              void* d_out, int out_size, void* d_ws, size_t ws_size,
                              hipStream_t stream)
{
  const float* x       = (const float*)d_in[0];
  const float* adj     = (const float*)d_in[1];
  const float* x_deq   = (const float*)d_in[2];
  const float* adj_deq = (const float*)d_in[3];
  const void*  mn_src  = d_in[4];
  const void*  me_src  = d_in[5];
  const int*   isel    = (const int*)d_in[6];
  const float* emb_w   = (const float*)d_in[7];
  const float* gw      = (const float*)d_in[8];
  const float* gb      = (const float*)d_in[9];
  const float* nw1     = (const float*)d_in[10];
  const float* nb1     = (const float*)d_in[11];
  const float* nw2     = (const float*)d_in[12];
  const float* nb2     = (const float*)d_in[13];
  const float* ew1     = (const float*)d_in[14];
  const float* eb1     = (const float*)d_in[15];
  const float* ew2     = (const float*)d_in[16];
  const float* eb2     = (const float*)d_in[17];

  char* ws = (char*)d_ws;
  uint8_t* mn            = (uint8_t*)(ws + WS_MN);
  uint8_t* me            = (uint8_t*)(ws + WS_ME);
  float* h0              = (float*)(ws + WS_H0);
  unsigned short* St     = (unsigned short*)(ws + WS_ST);
  unsigned short* gwt    = (unsigned short*)(ws + WS_GWT);
  unsigned short* nwt    = (unsigned short*)(ws + WS_NWT);
  unsigned short* ewt    = (unsigned short*)(ws + WS_EWT);
  unsigned short* gnb    = (unsigned short*)(ws + WS_GNB);
  unsigned short* gedge  = (unsigned short*)(ws + WS_GEDGE);
  float* sn              = (float*)(ws + WS_SN);
  float* tn              = (float*)(ws + WS_TN);
  float* se              = (float*)(ws + WS_SE);
  float* te              = (float*)(ws + WS_TE);
  float* partials        = (float*)(ws + WS_PART);

  const int NW_TOT = 9 * 128 * 128 + 12 * 128 * 128 + 12 * 128 * 384;

  prep_masks<<<256, 256, 0, stream>>>(mn_src, me_src, mn, me);
  prep_weights<<<(NW_TOT + 255) / 256, 256, 0, stream>>>(gw, nw1, ew1, gwt, nwt, ewt);
  h0_kernel<<<(Bc * Nn * Hh + 255) / 256, 256, 0, stream>>>(x, emb_w, h0);
  s_kernel<<<(Bc * GL * Hh * 64 + 255) / 256, 256, 0, stream>>>(h0, gw, St);
  gcn_mfma_kernel<<<Bc * Rr, 256, 0, stream>>>(adj, mn, me, St, gwt, gb, isel, gnb, gedge);
  st_mfma_kernel<128, NTc, Bc * Nn><<<Ll * ((Bc * Nn + 31) / 32), 256, 0, stream>>>(
      gnb, nwt, nb1, nw2, nb2, sn, tn);
  st_mfma_kernel<384, ETc, Bc * Ee><<<Ll * ((Bc * Ee + 31) / 32), 256, 0, stream>>>(
      gedge, ewt, eb1, ew2, eb2, se, te);
  combine_part<<<Bc * 8, 256, 0, stream>>>(x_deq, adj_deq, sn, tn, se, te, (float*)d_out, partials);
  combine_lj<<<1, 64, 0, stream>>>(partials, (float*)d_out);
}

// Round 10
// 330.517 us; speedup vs baseline: 4.2605x; 1.0221x over previous
//
#include <hip/hip_runtime.h>
#include <stdint.h>
#include <math.h>

#define Bc   8
#define Nn   38
#define NTc  9
#define ETc  4
#define Rr   416
#define Ee   378
#define Hh   128
#define Ll   12
#define GL   3

typedef __attribute__((ext_vector_type(8))) short s16x8;
typedef __attribute__((ext_vector_type(4))) short s16x4;
typedef __attribute__((ext_vector_type(4))) float f32x4;

// ---------------- workspace layout (bytes) ----------------
static const size_t WS_MN    = 0;
static const size_t WS_ME    = 15872;
static const size_t WS_H0    = 616576;
static const size_t WS_ST    = 772224;    // bf16 S^T [b*3+e][col][m pad 64]
static const size_t WS_GWT   = 1165440;   // bf16 gc W^T
static const size_t WS_NWT   = 1460352;   // bf16 nw1^T
static const size_t WS_EWT   = 1853568;   // bf16 ew1^T
static const size_t WS_GNB   = 3033216;   // bf16 gnode
static const size_t WS_GEDGE = 3111040;   // bf16
static const size_t WS_SN    = 5433472;
static const size_t WS_TN    = 5564800;
static const size_t WS_SE    = 5696128;
static const size_t WS_TE    = 6276736;
static const size_t WS_PART  = 6857344;

__device__ __forceinline__ unsigned short f2bf(float f) {
  unsigned u = __float_as_uint(f);
  u += 0x7FFFu + ((u >> 16) & 1u);       // RNE
  return (unsigned short)(u >> 16);
}
__device__ __forceinline__ float bf2f(unsigned short h) {
  return __uint_as_float(((unsigned)h) << 16);
}

__device__ __forceinline__ uint8_t mval(const void* src, int i, int mode) {
  if (mode == 0) return ((const int*)src)[i] != 0;
  if (mode == 1) return ((const float*)src)[i] != 0.0f;
  return ((const uint8_t*)src)[i] != 0;
}

__global__ void prep_masks(const void* __restrict__ mn_src, const void* __restrict__ me_src,
                           uint8_t* __restrict__ mn_dst, uint8_t* __restrict__ me_dst)
{
  __shared__ int s01, sf;
  if (threadIdx.x == 0) { s01 = 1; sf = 1; }
  __syncthreads();
  const uint32_t* p = (const uint32_t*)me_src;
  bool a01 = true, af = true;
  for (int i = threadIdx.x; i < 256; i += blockDim.x) {
    uint32_t v = p[i];
    if (v > 1u) a01 = false;
    if (v != 0u && v != 0x3f800000u) af = false;
  }
  if (!a01) atomicAnd(&s01, 0);
  if (!af)  atomicAnd(&sf, 0);
  __syncthreads();
  const int mode = s01 ? 0 : (sf ? 1 : 2);

  const int n_node = Rr * Nn;
  const int n_edge = Rr * Nn * Nn;
  const int tot = n_node + n_edge;
  for (int i = blockIdx.x * blockDim.x + threadIdx.x; i < tot; i += gridDim.x * blockDim.x) {
    if (i < n_node) mn_dst[i] = mval(mn_src, i, mode);
    else            me_dst[i - n_node] = mval(me_src, i - n_node, mode);
  }
}

// transpose+cast all three W1-style weight tensors to bf16 [..][col][k]
__global__ void prep_weights(const float* __restrict__ gw, const float* __restrict__ nw1,
                             const float* __restrict__ ew1,
                             unsigned short* __restrict__ gwt, unsigned short* __restrict__ nwt,
                             unsigned short* __restrict__ ewt)
{
  const int NG = 9 * 128 * 128;
  const int NNw = 12 * 128 * 128;
  const int NEw = 12 * 128 * 384;
  int idx = blockIdx.x * blockDim.x + threadIdx.x;
  if (idx < NG) {
    int k = idx & 127, col = (idx >> 7) & 127, le = idx >> 14;
    gwt[idx] = f2bf(gw[((size_t)le * 128 + k) * 128 + col]);
  } else if (idx < NG + NNw) {
    int j = idx - NG;
    int k = j & 127, col = (j >> 7) & 127, i = j >> 14;
    nwt[j] = f2bf(nw1[((size_t)i * 128 + k) * 128 + col]);
  } else if (idx < NG + NNw + NEw) {
    int j = idx - NG - NNw;
    int k = j % 384; int rem = j / 384;
    int col = rem & 127, i = rem >> 7;
    ewt[j] = f2bf(ew1[((size_t)i * 384 + k) * 128 + col]);
  }
}

__global__ void h0_kernel(const float* __restrict__ x, const float* __restrict__ emb_w,
                          float* __restrict__ h0)
{
  int idx = blockIdx.x * blockDim.x + threadIdx.x;
  if (idx >= Bc * Nn * Hh) return;
  int bn = idx >> 7, o = idx & 127;
  float acc = 0.0f;
  #pragma unroll
  for (int i = 0; i < NTc; ++i) acc += x[bn * NTc + i] * emb_w[i * Hh + o];
  h0[idx] = acc;
}

// St[(b*3+e)*128 + col][m(0..63)] = bf16( sum_k h0[b,m,k] * gw[0,e,k,col] ), m>=38 -> 0
__global__ void s_kernel(const float* __restrict__ h0, const float* __restrict__ gw,
                         unsigned short* __restrict__ St)
{
  int idx = blockIdx.x * blockDim.x + threadIdx.x;
  if (idx >= Bc * GL * Hh * 64) return;
  int m = idx & 63;
  int col = (idx >> 6) & 127;
  int t = idx >> 13;
  int e = t % GL, b = t / GL;
  float acc = 0.0f;
  if (m < Nn)
    for (int k = 0; k < Hh; ++k)
      acc += h0[(b * Nn + m) * Hh + k] * gw[((size_t)e * Hh + k) * Hh + col];
  St[idx] = (m < Nn) ? f2bf(acc) : (unsigned short)0;
}

// One block per (b,r). bf16 MFMA GCN.
// Layer 0: B-frags direct from global St with node-mask AND (no staging).
// Layers 1-2: supT LDS round-trip, barrier-free (intra-wave cols [32wv,32wv+32)).
// supT logical rows 48..63 are zero-filled ONCE (GEMM1 never writes them; GEMM2
// reads them — round-9 NaN was this uninitialized-LDS read, 0 x NaN = NaN).
__global__ __launch_bounds__(256, 3)
void gcn_mfma_kernel(const float* __restrict__ adj, const uint8_t* __restrict__ mn,
                     const uint8_t* __restrict__ me, const unsigned short* __restrict__ St,
                     const unsigned short* __restrict__ gwt, const float* __restrict__ gb,
                     const int* __restrict__ isel,
                     unsigned short* __restrict__ gnb, unsigned short* __restrict__ gedge)
{
  __shared__ char smem[47744];
  unsigned short* h_lds  = (unsigned short*)smem;             // 48*128*2 = 12288
  unsigned short* supT   = (unsigned short*)(smem + 12288);   // 128*64*2 = 16384
  unsigned short* am_lds = (unsigned short*)(smem + 28672);   // 3*48*64*2 = 18432
  float*          ge     = (float*)(smem + 47104);            // 512
  unsigned char*  mnu    = (unsigned char*)(smem + 47616);    // 64

  const int tid = threadIdx.x;
  const int b = blockIdx.x / Rr;
  const int r = blockIdx.x - b * Rr;
  const int lane = tid & 63;
  const int wv = tid >> 6;
  const int lo = lane & 15;          // A row / B,D col within 16-tile
  const int q  = lane >> 4;          // k-group (A/B), row-group (D)
  const int swz = (lo & 7) << 3;     // LDS element-XOR swizzle
  const int ct0 = 2 * wv;            // this wave's first col-tile

  // ---- stage am (edge-masked adj, zero-padded to 48x64) + node mask ----
  for (int idx = tid; idx < GL * 48 * 64; idx += 256) {
    int e = idx / (48 * 64);
    int rem = idx - e * (48 * 64);
    int n = rem >> 6, m = rem & 63;
    float v = 0.0f;
    if (n < Nn && m < Nn && me[r * (Nn * Nn) + n * Nn + m])
      v = adj[((b * ETc + e) * Nn + n) * Nn + m];
    am_lds[e * 3072 + n * 64 + (m ^ ((n & 7) << 3))] = f2bf(v);
  }
  if (tid < 64) mnu[tid] = (tid < Nn) ? mn[r * Nn + tid] : 0;

  // ---- zero supT logical rows 48..63 (swizzle-correct; col = tid>>1 is in this
  //      wave's own column range, so later same-wave reads are lgkmcnt-ordered) ----
  {
    int zcol = tid >> 1, zhalf = tid & 1;
    int zsw = (zcol & 7) << 3;
    *(s16x8*)&supT[zcol * 64 + ((48 + 8 * zhalf) ^ zsw)] = (s16x8){0,0,0,0,0,0,0,0};
  }
  __syncthreads();                                           // B1: am/mnu/supT-tail ready

  // per-lane node-mask dwords for layer-0 B (k = 32*ks + 8*q + 2*d + {0,1})
  uint32_t mkm[2][4];
  #pragma unroll
  for (int ks = 0; ks < 2; ++ks)
    #pragma unroll
    for (int d = 0; d < 4; ++d) {
      int k0 = 32 * ks + 8 * q + 2 * d;
      mkm[ks][d] = (mnu[k0] ? 0x0000FFFFu : 0u) | (mnu[k0 + 1] ? 0xFFFF0000u : 0u);
    }

  float bias[GL][2];
  #pragma unroll
  for (int l = 0; l < GL; ++l)
    #pragma unroll
    for (int ci = 0; ci < 2; ++ci)
      bias[l][ci] = gb[l * Hh + 16 * (ct0 + ci) + lo];

  f32x4 outacc[3][2];

  // ================= layer 0: out = sum_e am[e] @ (mask ⊙ S[b,e]) =================
  #pragma unroll
  for (int ci = 0; ci < 2; ++ci) {
    f32x4 bv = {bias[0][ci], bias[0][ci], bias[0][ci], bias[0][ci]};
    outacc[0][ci] = bv; outacc[1][ci] = bv; outacc[2][ci] = bv;
  }
  #pragma unroll
  for (int e = 0; e < GL; ++e) {
    const unsigned short* Sb = St + (size_t)(b * GL + e) * 128 * 64;
    #pragma unroll
    for (int ks = 0; ks < 2; ++ks) {
      union { s16x8 v; uint32_t u[4]; } B0, B1;
      B0.v = *(const s16x8*)(Sb + (16 * ct0 + lo) * 64 + 32 * ks + 8 * q);
      B1.v = *(const s16x8*)(Sb + (16 * ct0 + 16 + lo) * 64 + 32 * ks + 8 * q);
      #pragma unroll
      for (int d = 0; d < 4; ++d) { B0.u[d] &= mkm[ks][d]; B1.u[d] &= mkm[ks][d]; }
      #pragma unroll
      for (int rt = 0; rt < 3; ++rt) {
        s16x8 a = *(const s16x8*)&am_lds[e * 3072 + (lo + 16 * rt) * 64 + ((8 * q + 32 * ks) ^ swz)];
        outacc[rt][0] = __builtin_amdgcn_mfma_f32_16x16x32_bf16(a, B0.v, outacc[rt][0], 0, 0, 0);
        outacc[rt][1] = __builtin_amdgcn_mfma_f32_16x16x32_bf16(a, B1.v, outacc[rt][1], 0, 0, 0);
      }
    }
  }
  // write h (relu); h not read by anyone before B2
  #pragma unroll
  for (int rt = 0; rt < 3; ++rt)
    #pragma unroll
    for (int ci = 0; ci < 2; ++ci) {
      int col = 16 * (ct0 + ci) + lo;
      #pragma unroll
      for (int j = 0; j < 4; ++j) {
        int row = 16 * rt + 4 * q + j;
        h_lds[row * 128 + (col ^ ((row & 7) << 3))] = f2bf(fmaxf(outacc[rt][ci][j], 0.0f));
      }
    }
  __syncthreads();                                           // B2: h(0) visible

  // ================= layers 1..2 =================
  #pragma unroll
  for (int l = 1; l < GL; ++l) {
    #pragma unroll
    for (int ci = 0; ci < 2; ++ci) {
      f32x4 bv = {bias[l][ci], bias[l][ci], bias[l][ci], bias[l][ci]};
      outacc[0][ci] = bv; outacc[1][ci] = bv; outacc[2][ci] = bv;
    }

    for (int e = 0; e < GL; ++e) {
      // ---- GEMM1: sup = h @ W[l,e]  (M=48, N=128, K=128) ----
      f32x4 sa[3][2];
      #pragma unroll
      for (int rt = 0; rt < 3; ++rt)
        #pragma unroll
        for (int ci = 0; ci < 2; ++ci)
          sa[rt][ci] = (f32x4){0.f, 0.f, 0.f, 0.f};

      const unsigned short* wb = gwt + (size_t)(l * GL + e) * (Hh * Hh);
      #pragma unroll
      for (int ks = 0; ks < 4; ++ks) {
        int k0 = 8 * q + 32 * ks;
        s16x8 b0 = *(const s16x8*)(wb + (16 * ct0 + lo) * 128 + k0);
        s16x8 b1 = *(const s16x8*)(wb + (16 * ct0 + 16 + lo) * 128 + k0);
        #pragma unroll
        for (int rt = 0; rt < 3; ++rt) {
          s16x8 a = *(const s16x8*)&h_lds[(lo + 16 * rt) * 128 + (k0 ^ swz)];
          sa[rt][0] = __builtin_amdgcn_mfma_f32_16x16x32_bf16(a, b0, sa[rt][0], 0, 0, 0);
          sa[rt][1] = __builtin_amdgcn_mfma_f32_16x16x32_bf16(a, b1, sa[rt][1], 0, 0, 0);
        }
      }

      // ---- D -> supT rows 0..47 (cols [32wv,32wv+32): intra-wave, no barrier) ----
      #pragma unroll
      for (int rt = 0; rt < 3; ++rt)
        #pragma unroll
        for (int ci = 0; ci < 2; ++ci) {
          int col = 16 * (ct0 + ci) + lo;
          s16x4 pk;
          #pragma unroll
          for (int j = 0; j < 4; ++j) pk[j] = (short)f2bf(sa[rt][ci][j]);
          int k0 = 16 * rt + 4 * q;
          *(s16x4*)&supT[col * 64 + (k0 ^ swz)] = pk;
        }

      // ---- GEMM2: out += am[e] @ sup (reads only own cols; lgkmcnt orders) ----
      #pragma unroll
      for (int ks = 0; ks < 2; ++ks) {
        int k0 = 8 * q + 32 * ks;
        s16x8 b0 = *(const s16x8*)&supT[(16 * ct0 + lo) * 64 + (k0 ^ swz)];
        s16x8 b1 = *(const s16x8*)&supT[(16 * ct0 + 16 + lo) * 64 + (k0 ^ swz)];
        #pragma unroll
        for (int rt = 0; rt < 3; ++rt) {
          s16x8 a = *(const s16x8*)&am_lds[e * 3072 + (lo + 16 * rt) * 64 + (k0 ^ swz)];
          outacc[rt][0] = __builtin_amdgcn_mfma_f32_16x16x32_bf16(a, b0, outacc[rt][0], 0, 0, 0);
          outacc[rt][1] = __builtin_amdgcn_mfma_f32_16x16x32_bf16(a, b1, outacc[rt][1], 0, 0, 0);
        }
      }
    }

    __syncthreads();   // all waves done reading h(l-1)
    #pragma unroll
    for (int rt = 0; rt < 3; ++rt)
      #pragma unroll
      for (int ci = 0; ci < 2; ++ci) {
        int col = 16 * (ct0 + ci) + lo;
        #pragma unroll
        for (int j = 0; j < 4; ++j) {
          int row = 16 * rt + 4 * q + j;
          float v = outacc[rt][ci][j];
          if (l < GL - 1) v = fmaxf(v, 0.0f);
          h_lds[row * 128 + (col ^ ((row & 7) << 3))] = f2bf(v);
        }
      }
    __syncthreads();   // h(l) visible
  }

  // ---- epilogue: graph_emb + outputs ----
  if (tid < 128) {
    float s = 0.0f;
    for (int n = 0; n < Nn; ++n)
      s += bf2f(h_lds[n * 128 + (tid ^ ((n & 7) << 3))]);
    ge[tid] = s;
  }
  __syncthreads();

  if (r < Nn) {
    if (tid < 128) gnb[(size_t)(b * Nn + r) * Hh + tid] = f2bf(ge[tid]);
  } else {
    int ei = r - Nn;
    int i0 = isel[2 * ei], i1 = isel[2 * ei + 1];
    unsigned short* dst = gedge + (size_t)(b * Ee + ei) * 384;
    if (tid < 128) {
      dst[tid]        = h_lds[i0 * 128 + (tid ^ ((i0 & 7) << 3))];
      dst[128 + tid]  = h_lds[i1 * 128 + (tid ^ ((i1 & 7) << 3))];
      dst[256 + tid]  = f2bf(ge[tid]);
    }
  }
}

// ST MLP via MFMA: A [ROWS][IN_W] bf16, wt [12][128][IN_W] bf16, out s/t [12][ROWS][OUT_D]
template<int IN_W, int OUT_D, int ROWS>
__global__ __launch_bounds__(256)
void st_mfma_kernel(const unsigned short* __restrict__ A,
                    const unsigned short* __restrict__ wt,
                    const float* __restrict__ b1,
                    const float* __restrict__ w2,
                    const float* __restrict__ b2,
                    float* __restrict__ s_out, float* __restrict__ t_out)
{
  constexpr int MT = (ROWS + 31) / 32;
  constexpr int OD2 = 2 * OUT_D;
  __shared__ unsigned short hid[32 * 136];
  const int tid = threadIdx.x;
  const int i = blockIdx.x / MT;
  const int mt = blockIdx.x - i * MT;
  const int row0 = mt * 32;
  const int lane = tid & 63, wv = tid >> 6;
  const int lo = lane & 15, q = lane >> 4;

  f32x4 acc[2][2];
  #pragma unroll
  for (int rt = 0; rt < 2; ++rt)
    #pragma unroll
    for (int ci = 0; ci < 2; ++ci)
      acc[rt][ci] = (f32x4){0.f, 0.f, 0.f, 0.f};

  int ra = row0 + lo;       if (ra >= ROWS) ra = 0;
  int rb = row0 + 16 + lo;  if (rb >= ROWS) rb = 0;
  const unsigned short* Ap0 = A + (size_t)ra * IN_W;
  const unsigned short* Ap1 = A + (size_t)rb * IN_W;
  const unsigned short* Bp0 = wt + ((size_t)i * 128 + 32 * wv + lo) * IN_W;
  const unsigned short* Bp1 = wt + ((size_t)i * 128 + 32 * wv + 16 + lo) * IN_W;

  #pragma unroll
  for (int ks = 0; ks < IN_W / 32; ++ks) {
    int k0 = 8 * q + 32 * ks;
    s16x8 a0 = *(const s16x8*)(Ap0 + k0);
    s16x8 a1 = *(const s16x8*)(Ap1 + k0);
    s16x8 b0 = *(const s16x8*)(Bp0 + k0);
    s16x8 b1 = *(const s16x8*)(Bp1 + k0);
    acc[0][0] = __builtin_amdgcn_mfma_f32_16x16x32_bf16(a0, b0, acc[0][0], 0, 0, 0);
    acc[0][1] = __builtin_amdgcn_mfma_f32_16x16x32_bf16(a0, b1, acc[0][1], 0, 0, 0);
    acc[1][0] = __builtin_amdgcn_mfma_f32_16x16x32_bf16(a1, b0, acc[1][0], 0, 0, 0);
    acc[1][1] = __builtin_amdgcn_mfma_f32_16x16x32_bf16(a1, b1, acc[1][1], 0, 0, 0);
  }

  #pragma unroll
  for (int rt = 0; rt < 2; ++rt)
    #pragma unroll
    for (int ci = 0; ci < 2; ++ci) {
      int col = 32 * wv + 16 * ci + lo;
      float bb = b1[i * 128 + col];
      #pragma unroll
      for (int j = 0; j < 4; ++j) {
        int row = 16 * rt + 4 * q + j;
        hid[row * 136 + col] = f2bf(tanhf(acc[rt][ci][j] + bb));
      }
    }
  __syncthreads();

  for (int idx = tid; idx < 32 * OD2; idx += 256) {
    int lr = idx / OD2, c = idx - lr * OD2;
    int gr = row0 + lr;
    if (gr < ROWS) {
      float a = b2[i * OD2 + c];
      for (int k = 0; k < 128; ++k)
        a += bf2f(hid[lr * 136 + k]) * w2[((size_t)i * 128 + k) * OD2 + c];
      if (c < OUT_D) s_out[((size_t)i * ROWS + gr) * OUT_D + c] = 1.0f / (1.0f + expf(-(a + 2.0f)));
      else           t_out[((size_t)i * ROWS + gr) * OUT_D + (c - OUT_D)] = a;
    }
  }
}

// per-element 12-layer fold + partial log-jacobians (8 chunks per b)
__global__ __launch_bounds__(256)
void combine_part(const float* __restrict__ x_deq, const float* __restrict__ adj_deq,
                  const float* __restrict__ sn, const float* __restrict__ tn,
                  const float* __restrict__ se, const float* __restrict__ te,
                  float* __restrict__ out, float* __restrict__ partials)
{
  const int blk = blockIdx.x, tid = threadIdx.x;
  const int b = blk >> 3, ch = blk & 7;
  float ljx = 0.0f, lja = 0.0f;

  for (int j = ch * 256 + tid; j < Nn * NTc; j += 2048) {
    int n = j / NTc, c = j - n * NTc;
    int row = b * Nn + n;
    float v = x_deq[b * (Nn * NTc) + j];
    #pragma unroll
    for (int i = 0; i < Ll; ++i) {
      float s = sn[((size_t)i * (Bc * Nn) + row) * NTc + c];
      float t = tn[((size_t)i * (Bc * Nn) + row) * NTc + c];
      v = v * s + t;
      ljx += logf(fabsf(s) + 1e-20f);
    }
    out[b * (Nn * NTc) + j] = v;
  }

  for (int j = ch * 256 + tid; j < Ee * ETc; j += 2048) {
    int e = j / ETc, c = j - e * ETc;
    int row = b * Ee + e;
    float v = adj_deq[b * (Ee * ETc) + j];
    #pragma unroll
    for (int i = 0; i < Ll; ++i) {
      float s = se[((size_t)i * (Bc * Ee) + row) * ETc + c];
      float t = te[((size_t)i * (Bc * Ee) + row) * ETc + c];
      v = v * s + t;
      lja += logf(fabsf(s) + 1e-20f);
    }
    out[Bc * Nn * NTc + b * (Ee * ETc) + j] = v;
  }

  __shared__ float red[256];
  red[tid] = ljx; __syncthreads();
  for (int st = 128; st > 0; st >>= 1) { if (tid < st) red[tid] += red[tid + st]; __syncthreads(); }
  if (tid == 0) partials[blk] = red[0];
  __syncthreads();
  red[tid] = lja; __syncthreads();
  for (int st = 128; st > 0; st >>= 1) { if (tid < st) red[tid] += red[tid + st]; __syncthreads(); }
  if (tid == 0) partials[64 + blk] = red[0];
}

__global__ void combine_lj(const float* __restrict__ partials, float* __restrict__ out)
{
  int tid = threadIdx.x;
  if (tid < Bc) {
    float sx = 0.0f, sa = 0.0f;
    #pragma unroll
    for (int ch = 0; ch < 8; ++ch) {
      sx += partials[tid * 8 + ch];
      sa += partials[64 + tid * 8 + ch];
    }
    out[Bc * Nn * NTc + Bc * Ee * ETc + tid] = sx;
    out[Bc * Nn * NTc + Bc * Ee * ETc + Bc + tid] = sa;
  }
}

extern "C" void kernel_launch(void* const* d_in, const int* in_sizes, int n_in,
                              void* d_out, int out_size, void* d_ws, size_t ws_size,
                              hipStream_t stream)
{
  const float* x       = (const float*)d_in[0];
  const float* adj     = (const float*)d_in[1];
  const float* x_deq   = (const float*)d_in[2];
  const float* adj_deq = (const float*)d_in[3];
  const void*  mn_src  = d_in[4];
  const void*  me_src  = d_in[5];
  const int*   isel    = (const int*)d_in[6];
  const float* emb_w   = (const float*)d_in[7];
  const float* gw      = (const float*)d_in[8];
  const float* gb      = (const float*)d_in[9];
  const float* nw1     = (const float*)d_in[10];
  const float* nb1     = (const float*)d_in[11];
  const float* nw2     = (const float*)d_in[12];
  const float* nb2     = (const float*)d_in[13];
  const float* ew1     = (const float*)d_in[14];
  const float* eb1     = (const float*)d_in[15];
  const float* ew2     = (const float*)d_in[16];
  const float* eb2     = (const float*)d_in[17];

  char* ws = (char*)d_ws;
  uint8_t* mn            = (uint8_t*)(ws + WS_MN);
  uint8_t* me            = (uint8_t*)(ws + WS_ME);
  float* h0              = (float*)(ws + WS_H0);
  unsigned short* St     = (unsigned short*)(ws + WS_ST);
  unsigned short* gwt    = (unsigned short*)(ws + WS_GWT);
  unsigned short* nwt    = (unsigned short*)(ws + WS_NWT);
  unsigned short* ewt    = (unsigned short*)(ws + WS_EWT);
  unsigned short* gnb    = (unsigned short*)(ws + WS_GNB);
  unsigned short* gedge  = (unsigned short*)(ws + WS_GEDGE);
  float* sn              = (float*)(ws + WS_SN);
  float* tn              = (float*)(ws + WS_TN);
  float* se              = (float*)(ws + WS_SE);
  float* te              = (float*)(ws + WS_TE);
  float* partials        = (float*)(ws + WS_PART);

  const int NW_TOT = 9 * 128 * 128 + 12 * 128 * 128 + 12 * 128 * 384;

  prep_masks<<<256, 256, 0, stream>>>(mn_src, me_src, mn, me);
  prep_weights<<<(NW_TOT + 255) / 256, 256, 0, stream>>>(gw, nw1, ew1, gwt, nwt, ewt);
  h0_kernel<<<(Bc * Nn * Hh + 255) / 256, 256, 0, stream>>>(x, emb_w, h0);
  s_kernel<<<(Bc * GL * Hh * 64 + 255) / 256, 256, 0, stream>>>(h0, gw, St);
  gcn_mfma_kernel<<<Bc * Rr, 256, 0, stream>>>(adj, mn, me, St, gwt, gb, isel, gnb, gedge);
  st_mfma_kernel<128, NTc, Bc * Nn><<<Ll * ((Bc * Nn + 31) / 32), 256, 0, stream>>>(
      gnb, nwt, nb1, nw2, nb2, sn, tn);
  st_mfma_kernel<384, ETc, Bc * Ee><<<Ll * ((Bc * Ee + 31) / 32), 256, 0, stream>>>(
      gedge, ewt, eb1, ew2, eb2, se, te);
  combine_part<<<Bc * 8, 256, 0, stream>>>(x_deq, adj_deq, sn, tn, se, te, (float*)d_out, partials);
  combine_lj<<<1, 64, 0, stream>>>(partials, (float*)d_out);
}

// Round 11
// 291.697 us; speedup vs baseline: 4.8275x; 1.1331x over previous
//
#include <hip/hip_runtime.h>
#include <stdint.h>
#include <math.h>

#define Bc   8
#define Nn   38
#define NTc  9
#define ETc  4
#define Rr   416
#define Ee   378
#define Hh   128
#define Ll   12
#define GL   3

typedef __attribute__((ext_vector_type(8))) short s16x8;
typedef __attribute__((ext_vector_type(4))) short s16x4;
typedef __attribute__((ext_vector_type(4))) float f32x4;

// ---------------- workspace layout (bytes) ----------------
// Aliasing is temporally safe: MEP/H0 are dead before SN/TN/SE/TE/PART are written.
static const size_t WS_MN    = 0;         // 15808 -> 15872
static const size_t WS_MEP   = 15872;     // 416*48*64 u8 = 1277952 -> 1293824 (dead after gcn)
static const size_t WS_SN    = 15872;     // 131328   (written by node_st, after gcn)
static const size_t WS_TN    = 147200;    // 131328
static const size_t WS_SE    = 278528;    // 580608
static const size_t WS_TE    = 859136;    // 580608 -> 1439744 (spills into dead H0)
static const size_t WS_PART  = 1439744;   // 512 -> 1440256
static const size_t WS_H0    = 1293824;   // 155648 -> 1449472 (dead after s_kernel)
static const size_t WS_ST    = 1449472;   // 393216 -> 1842688 (bf16 S^T, m pad 64)
static const size_t WS_GWT   = 1842688;   // 294912 -> 2137600 (bf16 gc W^T)
static const size_t WS_NWT   = 2137600;   // 393216 -> 2530816 (bf16 nw1^T)
static const size_t WS_EWT   = 2530816;   // 1179648 -> 3710464 (bf16 ew1^T)
static const size_t WS_ADJP  = 3710464;   // 8*3*48*64 bf16 = 147456 -> 3857920
static const size_t WS_GNB   = 3857920;   // 77824 -> 3935744 (bf16 gnode)
static const size_t WS_GEDGE = 3935744;   // 2322432 -> 6258176 (bf16)

__device__ __forceinline__ unsigned short f2bf(float f) {
  unsigned u = __float_as_uint(f);
  u += 0x7FFFu + ((u >> 16) & 1u);       // RNE
  return (unsigned short)(u >> 16);
}
__device__ __forceinline__ float bf2f(unsigned short h) {
  return __uint_as_float(((unsigned)h) << 16);
}

__device__ __forceinline__ uint8_t mval(const void* src, int i, int mode) {
  if (mode == 0) return ((const int*)src)[i] != 0;
  if (mode == 1) return ((const float*)src)[i] != 0.0f;
  return ((const uint8_t*)src)[i] != 0;
}

// mn u8 [416][38]; mep u8 zero-padded [416][48][64]
__global__ void prep_masks(const void* __restrict__ mn_src, const void* __restrict__ me_src,
                           uint8_t* __restrict__ mn_dst, uint8_t* __restrict__ mep)
{
  __shared__ int s01, sf;
  if (threadIdx.x == 0) { s01 = 1; sf = 1; }
  __syncthreads();
  const uint32_t* p = (const uint32_t*)me_src;
  bool a01 = true, af = true;
  for (int i = threadIdx.x; i < 256; i += blockDim.x) {
    uint32_t v = p[i];
    if (v > 1u) a01 = false;
    if (v != 0u && v != 0x3f800000u) af = false;
  }
  if (!a01) atomicAnd(&s01, 0);
  if (!af)  atomicAnd(&sf, 0);
  __syncthreads();
  const int mode = s01 ? 0 : (sf ? 1 : 2);

  const int n_node = Rr * Nn;                 // 15808
  const int n_pad  = Rr * 48 * 64;            // 1277952
  for (int i = blockIdx.x * blockDim.x + threadIdx.x; i < n_node + n_pad;
       i += gridDim.x * blockDim.x) {
    if (i < n_node) {
      mn_dst[i] = mval(mn_src, i, mode);
    } else {
      int j = i - n_node;
      int m = j & 63, n = (j >> 6) & 47 - 0, r = j >> 6;  // placeholder; recompute below
      n = (j >> 6) % 48; r = j / (48 * 64);
      uint8_t v = 0;
      if (n < Nn && m < Nn) v = mval(me_src, r * (Nn * Nn) + n * Nn + m, mode);
      mep[j] = v;
    }
  }
}

// weights -> bf16 transposed; adj -> bf16 zero-padded [b][e][48][64]
__global__ void prep_weights(const float* __restrict__ gw, const float* __restrict__ nw1,
                             const float* __restrict__ ew1, const float* __restrict__ adj,
                             unsigned short* __restrict__ gwt, unsigned short* __restrict__ nwt,
                             unsigned short* __restrict__ ewt, unsigned short* __restrict__ adjp)
{
  const int NG  = 9 * 128 * 128;     // 147456
  const int NNw = 12 * 128 * 128;    // 196608
  const int NEw = 12 * 128 * 384;    // 589824
  const int NA  = Bc * GL * 48 * 64; // 73728
  int idx = blockIdx.x * blockDim.x + threadIdx.x;
  if (idx < NG) {
    int k = idx & 127, col = (idx >> 7) & 127, le = idx >> 14;
    gwt[idx] = f2bf(gw[((size_t)le * 128 + k) * 128 + col]);
  } else if (idx < NG + NNw) {
    int j = idx - NG;
    int k = j & 127, col = (j >> 7) & 127, i = j >> 14;
    nwt[j] = f2bf(nw1[((size_t)i * 128 + k) * 128 + col]);
  } else if (idx < NG + NNw + NEw) {
    int j = idx - NG - NNw;
    int k = j % 384; int rem = j / 384;
    int col = rem & 127, i = rem >> 7;
    ewt[j] = f2bf(ew1[((size_t)i * 384 + k) * 128 + col]);
  } else if (idx < NG + NNw + NEw + NA) {
    int j = idx - NG - NNw - NEw;
    int m = j & 63, n = (j >> 6) % 48, be = j / (48 * 64);
    int e = be % GL, b = be / GL;
    unsigned short v = 0;
    if (n < Nn && m < Nn) v = f2bf(adj[((b * ETc + e) * Nn + n) * Nn + m]);
    adjp[j] = v;
  }
}

__global__ void h0_kernel(const float* __restrict__ x, const float* __restrict__ emb_w,
                          float* __restrict__ h0)
{
  int idx = blockIdx.x * blockDim.x + threadIdx.x;
  if (idx >= Bc * Nn * Hh) return;
  int bn = idx >> 7, o = idx & 127;
  float acc = 0.0f;
  #pragma unroll
  for (int i = 0; i < NTc; ++i) acc += x[bn * NTc + i] * emb_w[i * Hh + o];
  h0[idx] = acc;
}

// St[(b*3+e)*128 + col][m(0..63)] = bf16( sum_k h0[b,m,k] * gw[0,e,k,col] ), m>=38 -> 0
__global__ void s_kernel(const float* __restrict__ h0, const float* __restrict__ gw,
                         unsigned short* __restrict__ St)
{
  int idx = blockIdx.x * blockDim.x + threadIdx.x;
  if (idx >= Bc * GL * Hh * 64) return;
  int m = idx & 63;
  int col = (idx >> 6) & 127;
  int t = idx >> 13;
  int e = t % GL, b = t / GL;
  float acc = 0.0f;
  if (m < Nn)
    for (int k = 0; k < Hh; ++k)
      acc += h0[(b * Nn + m) * Hh + k] * gw[((size_t)e * Hh + k) * Hh + col];
  St[idx] = (m < Nn) ? f2bf(acc) : (unsigned short)0;
}

// One block per (b,r). bf16 MFMA GCN, all LDS accesses vectorized.
// Layer 0 / GEMM2 use swapped operands (A = S^T / supT, B = am) so the D-frag
// holds 4 consecutive output-cols at a fixed row -> b64 h-writes.
__global__ __launch_bounds__(256, 3)
void gcn_mfma_kernel(const unsigned short* __restrict__ adjp, const uint8_t* __restrict__ mn,
                     const uint8_t* __restrict__ mep, const unsigned short* __restrict__ St,
                     const unsigned short* __restrict__ gwt, const float* __restrict__ gb,
                     const int* __restrict__ isel,
                     unsigned short* __restrict__ gnb, unsigned short* __restrict__ gedge)
{
  __shared__ char smem[47744];
  unsigned short* h_lds  = (unsigned short*)smem;             // 48*128*2 = 12288
  unsigned short* supT   = (unsigned short*)(smem + 12288);   // 128*64*2 = 16384
  unsigned short* am_lds = (unsigned short*)(smem + 28672);   // 3*48*64*2 = 18432
  float*          ge     = (float*)(smem + 47104);            // 512
  unsigned char*  mnu    = (unsigned char*)(smem + 47616);    // 64

  const int tid = threadIdx.x;
  const int b = blockIdx.x / Rr;
  const int r = blockIdx.x - b * Rr;
  const int lane = tid & 63;
  const int wv = tid >> 6;
  const int lo = lane & 15;
  const int q  = lane >> 4;
  const int swz = (lo & 7) << 3;
  const int ct0 = 2 * wv;            // wave's first c-tile (c in [32wv, 32wv+32))

  // ---- vectorized am staging: 8 elems per chunk ----
  for (int idx = tid; idx < GL * 48 * 8; idx += 256) {
    int e = idx / (48 * 8);
    int rem = idx - e * 384;
    int n = rem >> 3, m0 = (rem & 7) * 8;
    uint64_t mb = *(const uint64_t*)&mep[(size_t)r * 3072 + n * 64 + m0];
    s16x8 av = *(const s16x8*)&adjp[((size_t)(b * GL + e) * 48 + n) * 64 + m0];
    s16x8 o;
    #pragma unroll
    for (int i = 0; i < 8; ++i)
      o[i] = ((mb >> (8 * i)) & 0xffu) ? av[i] : (short)0;
    *(s16x8*)&am_lds[e * 3072 + n * 64 + (m0 ^ ((n & 7) << 3))] = o;
  }
  if (tid < 64) mnu[tid] = (tid < Nn) ? mn[r * Nn + tid] : 0;

  // zero supT logical rows 48..63 (read by A2-frag ks=1, q>=2; never written by GEMM1)
  {
    int zcol = tid >> 1, zhalf = tid & 1;
    int zsw = (zcol & 7) << 3;
    *(s16x8*)&supT[zcol * 64 + ((48 + 8 * zhalf) ^ zsw)] = (s16x8){0,0,0,0,0,0,0,0};
  }
  __syncthreads();                                           // B1

  // per-lane node-mask dwords for layer-0 A (m = 32*ks + 8*q + 2*d + {0,1})
  uint32_t mkm[2][4];
  #pragma unroll
  for (int ks = 0; ks < 2; ++ks)
    #pragma unroll
    for (int d = 0; d < 4; ++d) {
      int k0 = 32 * ks + 8 * q + 2 * d;
      mkm[ks][d] = (mnu[k0] ? 0x0000FFFFu : 0u) | (mnu[k0 + 1] ? 0xFFFF0000u : 0u);
    }

  f32x4 acc[3][2];   // [n-tile][c-tile]: R[c][n], c = 16*(ct0+ci)+4q+j, n = 16*nt+lo

  // ================= layer 0: R = sum_e (mask ⊙ S^T) @ am^T =================
  #pragma unroll
  for (int ci = 0; ci < 2; ++ci) {
    f32x4 b4 = *(const f32x4*)&gb[16 * (ct0 + ci) + 4 * q];
    acc[0][ci] = b4; acc[1][ci] = b4; acc[2][ci] = b4;
  }
  #pragma unroll
  for (int e = 0; e < GL; ++e) {
    const unsigned short* Sb = St + (size_t)(b * GL + e) * 128 * 64;
    #pragma unroll
    for (int ks = 0; ks < 2; ++ks) {
      int m0 = 32 * ks + 8 * q;
      union { s16x8 v; uint32_t u[4]; } A0, A1;
      A0.v = *(const s16x8*)(Sb + (16 * ct0 + lo) * 64 + m0);
      A1.v = *(const s16x8*)(Sb + (16 * (ct0 + 1) + lo) * 64 + m0);
      #pragma unroll
      for (int d = 0; d < 4; ++d) { A0.u[d] &= mkm[ks][d]; A1.u[d] &= mkm[ks][d]; }
      #pragma unroll
      for (int nt = 0; nt < 3; ++nt) {
        s16x8 bf = *(const s16x8*)&am_lds[e * 3072 + (16 * nt + lo) * 64 + (m0 ^ swz)];
        acc[nt][0] = __builtin_amdgcn_mfma_f32_16x16x32_bf16(A0.v, bf, acc[nt][0], 0, 0, 0);
        acc[nt][1] = __builtin_amdgcn_mfma_f32_16x16x32_bf16(A1.v, bf, acc[nt][1], 0, 0, 0);
      }
    }
  }
  // D -> h (relu), b64 writes: row n fixed, 4 consecutive c
  #pragma unroll
  for (int nt = 0; nt < 3; ++nt)
    #pragma unroll
    for (int ci = 0; ci < 2; ++ci) {
      int n = 16 * nt + lo;
      int c0 = 16 * (ct0 + ci) + 4 * q;
      s16x4 pk;
      #pragma unroll
      for (int j = 0; j < 4; ++j) pk[j] = (short)f2bf(fmaxf(acc[nt][ci][j], 0.0f));
      *(s16x4*)&h_lds[n * 128 + (c0 ^ ((n & 7) << 3))] = pk;
    }
  __syncthreads();                                           // B2: h(0) visible

  // ================= layers 1..2 =================
  #pragma unroll
  for (int l = 1; l < GL; ++l) {
    #pragma unroll
    for (int ci = 0; ci < 2; ++ci) {
      f32x4 b4 = *(const f32x4*)&gb[l * Hh + 16 * (ct0 + ci) + 4 * q];
      acc[0][ci] = b4; acc[1][ci] = b4; acc[2][ci] = b4;
    }

    for (int e = 0; e < GL; ++e) {
      // ---- GEMM1: sup = h @ W[l,e] (A = h rows, B = W^T cols) ----
      f32x4 sa[3][2];
      #pragma unroll
      for (int rt = 0; rt < 3; ++rt)
        #pragma unroll
        for (int ci = 0; ci < 2; ++ci)
          sa[rt][ci] = (f32x4){0.f, 0.f, 0.f, 0.f};

      const unsigned short* wb = gwt + (size_t)(l * GL + e) * (Hh * Hh);
      #pragma unroll
      for (int ks = 0; ks < 4; ++ks) {
        int k0 = 8 * q + 32 * ks;
        s16x8 b0 = *(const s16x8*)(wb + (16 * ct0 + lo) * 128 + k0);
        s16x8 b1 = *(const s16x8*)(wb + (16 * ct0 + 16 + lo) * 128 + k0);
        #pragma unroll
        for (int rt = 0; rt < 3; ++rt) {
          s16x8 a = *(const s16x8*)&h_lds[(lo + 16 * rt) * 128 + (k0 ^ swz)];
          sa[rt][0] = __builtin_amdgcn_mfma_f32_16x16x32_bf16(a, b0, sa[rt][0], 0, 0, 0);
          sa[rt][1] = __builtin_amdgcn_mfma_f32_16x16x32_bf16(a, b1, sa[rt][1], 0, 0, 0);
        }
      }

      // ---- D1 -> supT[c][m] (b64, intra-wave cols [32wv,32wv+32)) ----
      #pragma unroll
      for (int rt = 0; rt < 3; ++rt)
        #pragma unroll
        for (int ci = 0; ci < 2; ++ci) {
          int col = 16 * (ct0 + ci) + lo;
          s16x4 pk;
          #pragma unroll
          for (int j = 0; j < 4; ++j) pk[j] = (short)f2bf(sa[rt][ci][j]);
          int k0 = 16 * rt + 4 * q;
          *(s16x4*)&supT[col * 64 + (k0 ^ swz)] = pk;
        }

      // ---- GEMM2 (swapped): R[c][n] += supT[c][m] x am[n][m] ----
      #pragma unroll
      for (int ks = 0; ks < 2; ++ks) {
        int m0 = 32 * ks + 8 * q;
        s16x8 A2a = *(const s16x8*)&supT[(16 * ct0 + lo) * 64 + (m0 ^ swz)];
        s16x8 A2b = *(const s16x8*)&supT[(16 * (ct0 + 1) + lo) * 64 + (m0 ^ swz)];
        #pragma unroll
        for (int nt = 0; nt < 3; ++nt) {
          s16x8 bf = *(const s16x8*)&am_lds[e * 3072 + (16 * nt + lo) * 64 + (m0 ^ swz)];
          acc[nt][0] = __builtin_amdgcn_mfma_f32_16x16x32_bf16(A2a, bf, acc[nt][0], 0, 0, 0);
          acc[nt][1] = __builtin_amdgcn_mfma_f32_16x16x32_bf16(A2b, bf, acc[nt][1], 0, 0, 0);
        }
      }
    }

    __syncthreads();   // all waves done reading h(l-1)
    #pragma unroll
    for (int nt = 0; nt < 3; ++nt)
      #pragma unroll
      for (int ci = 0; ci < 2; ++ci) {
        int n = 16 * nt + lo;
        int c0 = 16 * (ct0 + ci) + 4 * q;
        s16x4 pk;
        #pragma unroll
        for (int j = 0; j < 4; ++j) {
          float v = acc[nt][ci][j];
          if (l < GL - 1) v = fmaxf(v, 0.0f);
          pk[j] = (short)f2bf(v);
        }
        *(s16x4*)&h_lds[n * 128 + (c0 ^ ((n & 7) << 3))] = pk;
      }
    __syncthreads();   // h(l) visible
  }

  // ---- epilogue: graph_emb + outputs ----
  if (tid < 128) {
    float s = 0.0f;
    for (int n = 0; n < Nn; ++n)
      s += bf2f(h_lds[n * 128 + (tid ^ ((n & 7) << 3))]);
    ge[tid] = s;
  }
  __syncthreads();

  if (r < Nn) {
    if (tid < 128) gnb[(size_t)(b * Nn + r) * Hh + tid] = f2bf(ge[tid]);
  } else {
    int ei = r - Nn;
    int i0 = isel[2 * ei], i1 = isel[2 * ei + 1];
    unsigned short* dst = gedge + (size_t)(b * Ee + ei) * 384;
    if (tid < 128) {
      dst[tid]        = h_lds[i0 * 128 + (tid ^ ((i0 & 7) << 3))];
      dst[128 + tid]  = h_lds[i1 * 128 + (tid ^ ((i1 & 7) << 3))];
      dst[256 + tid]  = f2bf(ge[tid]);
    }
  }
}

// ST MLP via MFMA: A [ROWS][IN_W] bf16, wt [12][128][IN_W] bf16, out s/t [12][ROWS][OUT_D]
template<int IN_W, int OUT_D, int ROWS>
__global__ __launch_bounds__(256)
void st_mfma_kernel(const unsigned short* __restrict__ A,
                    const unsigned short* __restrict__ wt,
                    const float* __restrict__ b1,
                    const float* __restrict__ w2,
                    const float* __restrict__ b2,
                    float* __restrict__ s_out, float* __restrict__ t_out)
{
  constexpr int MT = (ROWS + 31) / 32;
  constexpr int OD2 = 2 * OUT_D;
  __shared__ unsigned short hid[32 * 136];
  const int tid = threadIdx.x;
  const int i = blockIdx.x / MT;
  const int mt = blockIdx.x - i * MT;
  const int row0 = mt * 32;
  const int lane = tid & 63, wv = tid >> 6;
  const int lo = lane & 15, q = lane >> 4;

  f32x4 acc[2][2];
  #pragma unroll
  for (int rt = 0; rt < 2; ++rt)
    #pragma unroll
    for (int ci = 0; ci < 2; ++ci)
      acc[rt][ci] = (f32x4){0.f, 0.f, 0.f, 0.f};

  int ra = row0 + lo;       if (ra >= ROWS) ra = 0;
  int rb = row0 + 16 + lo;  if (rb >= ROWS) rb = 0;
  const unsigned short* Ap0 = A + (size_t)ra * IN_W;
  const unsigned short* Ap1 = A + (size_t)rb * IN_W;
  const unsigned short* Bp0 = wt + ((size_t)i * 128 + 32 * wv + lo) * IN_W;
  const unsigned short* Bp1 = wt + ((size_t)i * 128 + 32 * wv + 16 + lo) * IN_W;

  #pragma unroll
  for (int ks = 0; ks < IN_W / 32; ++ks) {
    int k0 = 8 * q + 32 * ks;
    s16x8 a0 = *(const s16x8*)(Ap0 + k0);
    s16x8 a1 = *(const s16x8*)(Ap1 + k0);
    s16x8 b0 = *(const s16x8*)(Bp0 + k0);
    s16x8 b1 = *(const s16x8*)(Bp1 + k0);
    acc[0][0] = __builtin_amdgcn_mfma_f32_16x16x32_bf16(a0, b0, acc[0][0], 0, 0, 0);
    acc[0][1] = __builtin_amdgcn_mfma_f32_16x16x32_bf16(a0, b1, acc[0][1], 0, 0, 0);
    acc[1][0] = __builtin_amdgcn_mfma_f32_16x16x32_bf16(a1, b0, acc[1][0], 0, 0, 0);
    acc[1][1] = __builtin_amdgcn_mfma_f32_16x16x32_bf16(a1, b1, acc[1][1], 0, 0, 0);
  }

  #pragma unroll
  for (int rt = 0; rt < 2; ++rt)
    #pragma unroll
    for (int ci = 0; ci < 2; ++ci) {
      int col = 32 * wv + 16 * ci + lo;
      float bb = b1[i * 128 + col];
      #pragma unroll
      for (int j = 0; j < 4; ++j) {
        int row = 16 * rt + 4 * q + j;
        hid[row * 136 + col] = f2bf(tanhf(acc[rt][ci][j] + bb));
      }
    }
  __syncthreads();

  for (int idx = tid; idx < 32 * OD2; idx += 256) {
    int lr = idx / OD2, c = idx - lr * OD2;
    int gr = row0 + lr;
    if (gr < ROWS) {
      float a = b2[i * OD2 + c];
      for (int k = 0; k < 128; ++k)
        a += bf2f(hid[lr * 136 + k]) * w2[((size_t)i * 128 + k) * OD2 + c];
      if (c < OUT_D) s_out[((size_t)i * ROWS + gr) * OUT_D + c] = 1.0f / (1.0f + expf(-(a + 2.0f)));
      else           t_out[((size_t)i * ROWS + gr) * OUT_D + (c - OUT_D)] = a;
    }
  }
}

// per-element 12-layer fold + partial log-jacobians (8 chunks per b)
__global__ __launch_bounds__(256)
void combine_part(const float* __restrict__ x_deq, const float* __restrict__ adj_deq,
                  const float* __restrict__ sn, const float* __restrict__ tn,
                  const float* __restrict__ se, const float* __restrict__ te,
                  float* __restrict__ out, float* __restrict__ partials)
{
  const int blk = blockIdx.x, tid = threadIdx.x;
  const int b = blk >> 3, ch = blk & 7;
  float ljx = 0.0f, lja = 0.0f;

  for (int j = ch * 256 + tid; j < Nn * NTc; j += 2048) {
    int n = j / NTc, c = j - n * NTc;
    int row = b * Nn + n;
    float v = x_deq[b * (Nn * NTc) + j];
    #pragma unroll
    for (int i = 0; i < Ll; ++i) {
      float s = sn[((size_t)i * (Bc * Nn) + row) * NTc + c];
      float t = tn[((size_t)i * (Bc * Nn) + row) * NTc + c];
      v = v * s + t;
      ljx += logf(fabsf(s) + 1e-20f);
    }
    out[b * (Nn * NTc) + j] = v;
  }

  for (int j = ch * 256 + tid; j < Ee * ETc; j += 2048) {
    int e = j / ETc, c = j - e * ETc;
    int row = b * Ee + e;
    float v = adj_deq[b * (Ee * ETc) + j];
    #pragma unroll
    for (int i = 0; i < Ll; ++i) {
      float s = se[((size_t)i * (Bc * Ee) + row) * ETc + c];
      float t = te[((size_t)i * (Bc * Ee) + row) * ETc + c];
      v = v * s + t;
      lja += logf(fabsf(s) + 1e-20f);
    }
    out[Bc * Nn * NTc + b * (Ee * ETc) + j] = v;
  }

  __shared__ float red[256];
  red[tid] = ljx; __syncthreads();
  for (int st = 128; st > 0; st >>= 1) { if (tid < st) red[tid] += red[tid + st]; __syncthreads(); }
  if (tid == 0) partials[blk] = red[0];
  __syncthreads();
  red[tid] = lja; __syncthreads();
  for (int st = 128; st > 0; st >>= 1) { if (tid < st) red[tid] += red[tid + st]; __syncthreads(); }
  if (tid == 0) partials[64 + blk] = red[0];
}

__global__ void combine_lj(const float* __restrict__ partials, float* __restrict__ out)
{
  int tid = threadIdx.x;
  if (tid < Bc) {
    float sx = 0.0f, sa = 0.0f;
    #pragma unroll
    for (int ch = 0; ch < 8; ++ch) {
      sx += partials[tid * 8 + ch];
      sa += partials[64 + tid * 8 + ch];
    }
    out[Bc * Nn * NTc + Bc * Ee * ETc + tid] = sx;
    out[Bc * Nn * NTc + Bc * Ee * ETc + Bc + tid] = sa;
  }
}

extern "C" void kernel_launch(void* const* d_in, const int* in_sizes, int n_in,
                              void* d_out, int out_size, void* d_ws, size_t ws_size,
                              hipStream_t stream)
{
  const float* x       = (const float*)d_in[0];
  const float* adj     = (const float*)d_in[1];
  const float* x_deq   = (const float*)d_in[2];
  const float* adj_deq = (const float*)d_in[3];
  const void*  mn_src  = d_in[4];
  const void*  me_src  = d_in[5];
  const int*   isel    = (const int*)d_in[6];
  const float* emb_w   = (const float*)d_in[7];
  const float* gw      = (const float*)d_in[8];
  const float* gb      = (const float*)d_in[9];
  const float* nw1     = (const float*)d_in[10];
  const float* nb1     = (const float*)d_in[11];
  const float* nw2     = (const float*)d_in[12];
  const float* nb2     = (const float*)d_in[13];
  const float* ew1     = (const float*)d_in[14];
  const float* eb1     = (const float*)d_in[15];
  const float* ew2     = (const float*)d_in[16];
  const float* eb2     = (const float*)d_in[17];

  char* ws = (char*)d_ws;
  uint8_t* mn            = (uint8_t*)(ws + WS_MN);
  uint8_t* mep           = (uint8_t*)(ws + WS_MEP);
  float* h0              = (float*)(ws + WS_H0);
  unsigned short* St     = (unsigned short*)(ws + WS_ST);
  unsigned short* gwt    = (unsigned short*)(ws + WS_GWT);
  unsigned short* nwt    = (unsigned short*)(ws + WS_NWT);
  unsigned short* ewt    = (unsigned short*)(ws + WS_EWT);
  unsigned short* adjp   = (unsigned short*)(ws + WS_ADJP);
  unsigned short* gnb    = (unsigned short*)(ws + WS_GNB);
  unsigned short* gedge  = (unsigned short*)(ws + WS_GEDGE);
  float* sn              = (float*)(ws + WS_SN);
  float* tn              = (float*)(ws + WS_TN);
  float* se              = (float*)(ws + WS_SE);
  float* te              = (float*)(ws + WS_TE);
  float* partials        = (float*)(ws + WS_PART);

  const int NW_TOT = 9 * 128 * 128 + 12 * 128 * 128 + 12 * 128 * 384 + Bc * GL * 48 * 64;

  prep_masks<<<256, 256, 0, stream>>>(mn_src, me_src, mn, mep);
  prep_weights<<<(NW_TOT + 255) / 256, 256, 0, stream>>>(gw, nw1, ew1, adj, gwt, nwt, ewt, adjp);
  h0_kernel<<<(Bc * Nn * Hh + 255) / 256, 256, 0, stream>>>(x, emb_w, h0);
  s_kernel<<<(Bc * GL * Hh * 64 + 255) / 256, 256, 0, stream>>>(h0, gw, St);
  gcn_mfma_kernel<<<Bc * Rr, 256, 0, stream>>>(adjp, mn, mep, St, gwt, gb, isel, gnb, gedge);
  st_mfma_kernel<128, NTc, Bc * Nn><<<Ll * ((Bc * Nn + 31) / 32), 256, 0, stream>>>(
      gnb, nwt, nb1, nw2, nb2, sn, tn);
  st_mfma_kernel<384, ETc, Bc * Ee><<<Ll * ((Bc * Ee + 31) / 32), 256, 0, stream>>>(
      gedge, ewt, eb1, ew2, eb2, se, te);
  combine_part<<<Bc * 8, 256, 0, stream>>>(x_deq, adj_deq, sn, tn, se, te, (float*)d_out, partials);
  combine_lj<<<1, 64, 0, stream>>>(partials, (float*)d_out);
}